// Round 14
// baseline (943.495 us; speedup 1.0000x reference)
//
#include <hip/hip_runtime.h>

// Bijective XCD-aware block swizzle (m204 variant; safe for nwg % 8 != 0).
__device__ __forceinline__ int xcd_swizzle(int bid, int nwg) {
    int q = nwg >> 3, r = nwg & 7;
    int xcd = bid & 7, idx = bid >> 3;
    return (xcd < r) ? xcd * (q + 1) + idx
                     : r * (q + 1) + (xcd - r) * q + idx;
}

// ---------------------------------------------------------------------------
// Stage 1 v2: conv1 (11x11, Cin=1, Cout=32) + ReLU + maxpool 3x3 s2 ceil.
// ---------------------------------------------------------------------------
__global__ __launch_bounds__(256, 4) void conv1_pool_v2_kernel(
    const float* __restrict__ x, const float* __restrict__ w,
    const float* __restrict__ bias, float* __restrict__ out)
{
    const int tile = blockIdx.x;          // 0..24
    const int cog  = blockIdx.y;          // 0..3  (8 couts each)
    const int b    = blockIdx.z;          // 0..31
    const int ty = tile / 5, tx = tile % 5;
    const int pr0 = ty * 16, pc0 = tx * 16;   // pooled origin
    const int cr0 = pr0 * 2, cc0 = pc0 * 2;   // conv origin

    __shared__ float in_s[43 * 44];
    __shared__ float w_s[8][121];
    __shared__ float hp_s[33][8][17];

    const int tid = threadIdx.x;

    const float* xb = x + b * 152 * 152;
    for (int i = tid; i < 43 * 44; i += 256) {
        int r = i / 44, c = i - r * 44;
        int ir = cr0 + r, ic = cc0 + c;
        in_s[i] = (ir < 152 && ic < 152) ? xb[ir * 152 + ic] : 0.f;
    }
    for (int i = tid; i < 8 * 121; i += 256) {
        int co = i / 121, k = i - co * 121;
        w_s[co][k] = w[(cog * 8 + co) * 121 + k];
    }
    __syncthreads();

    for (int task = tid; task < 264; task += 256) {
        const int co  = task & 7;
        const int row = task >> 3;
        float hmax[16];
        if (cr0 + row < 142) {
            float acc[33];
            #pragma unroll
            for (int px = 0; px < 33; ++px) acc[px] = 0.f;
            #pragma unroll 1
            for (int kh = 0; kh < 11; ++kh) {
                float4 rq[11];
                #pragma unroll
                for (int j = 0; j < 11; ++j)
                    rq[j] = *reinterpret_cast<const float4*>(
                        &in_s[(row + kh) * 44 + j * 4]);
                const float* rr = reinterpret_cast<const float*>(rq);
                #pragma unroll
                for (int kw = 0; kw < 11; ++kw) {
                    float wv = w_s[co][kh * 11 + kw];
                    #pragma unroll
                    for (int px = 0; px < 33; ++px)
                        acc[px] += rr[px + kw] * wv;
                }
            }
            const float bv = bias[cog * 8 + co];
            #pragma unroll
            for (int px = 0; px < 33; ++px) {
                float v = fmaxf(acc[px] + bv, 0.f);
                acc[px] = (cc0 + px < 142) ? v : 0.f;
            }
            #pragma unroll
            for (int pc = 0; pc < 16; ++pc)
                hmax[pc] = fmaxf(fmaxf(acc[2 * pc], acc[2 * pc + 1]), acc[2 * pc + 2]);
        } else {
            #pragma unroll
            for (int pc = 0; pc < 16; ++pc) hmax[pc] = 0.f;
        }
        #pragma unroll
        for (int pc = 0; pc < 16; ++pc) hp_s[row][co][pc] = hmax[pc];
    }
    __syncthreads();

    for (int t = tid; t < 2048; t += 256) {
        int co = t >> 8, r = t & 255;
        int ppy = r >> 4, ppc = r & 15;
        float v = fmaxf(fmaxf(hp_s[2 * ppy][co][ppc], hp_s[2 * ppy + 1][co][ppc]),
                        hp_s[2 * ppy + 2][co][ppc]);
        int pr = pr0 + ppy, pc = pc0 + ppc;
        if (pr < 71 && pc < 71)
            out[((b * 32 + cog * 8 + co) * 71 + pr) * 71 + pc] = v;
    }
}

// ---------------------------------------------------------------------------
// Stage 2: conv2 (9x9, Cin=32, Cout=16) + ReLU   (unchanged)
// ---------------------------------------------------------------------------
__global__ __launch_bounds__(256) void conv2_kernel(
    const float* __restrict__ in, const float* __restrict__ w,
    const float* __restrict__ bias, float* __restrict__ out)
{
    const int tile = blockIdx.x;
    const int b = blockIdx.y;
    const int ty = tile / 4, tx = tile % 4;
    const int oh0 = ty * 16, ow0 = tx * 16;

    __shared__ float in_s[4][24][25];
    __shared__ float w_s[16][324];

    const int tid = threadIdx.x;
    const int co = tid / 16;
    const int py = tid % 16;

    float acc[16];
    #pragma unroll
    for (int i = 0; i < 16; ++i) acc[i] = 0.f;

    for (int cc = 0; cc < 8; ++cc) {
        for (int i = tid; i < 4 * 24 * 24; i += 256) {
            int ci = i / 576, r = (i / 24) % 24, c = i % 24;
            int ih = oh0 + r, iw = ow0 + c;
            float v = 0.f;
            if (ih < 71 && iw < 71)
                v = in[((b * 32 + cc * 4 + ci) * 71 + ih) * 71 + iw];
            in_s[ci][r][c] = v;
        }
        for (int i = tid; i < 16 * 324; i += 256) {
            int c2 = i / 324, t = i % 324;
            w_s[c2][t] = w[c2 * 2592 + cc * 324 + t];
        }
        __syncthreads();

        #pragma unroll 1
        for (int ci = 0; ci < 4; ++ci) {
            #pragma unroll 1
            for (int kh = 0; kh < 9; ++kh) {
                float rr[24];
                #pragma unroll
                for (int c = 0; c < 24; ++c) rr[c] = in_s[ci][py + kh][c];
                #pragma unroll
                for (int kw = 0; kw < 9; ++kw) {
                    float wv = w_s[co][ci * 81 + kh * 9 + kw];
                    #pragma unroll
                    for (int px = 0; px < 16; ++px)
                        acc[px] += rr[kw + px] * wv;
                }
            }
        }
        __syncthreads();
    }

    const int oh = oh0 + py;
    if (oh < 63) {
        const float bv = bias[co];
        #pragma unroll
        for (int px = 0; px < 16; ++px) {
            int ow = ow0 + px;
            if (ow < 63)
                out[((b * 16 + co) * 63 + oh) * 63 + ow] = fmaxf(acc[px] + bv, 0.f);
        }
    }
}

// ---------------------------------------------------------------------------
// Stages 3-5 v11: locally-connected conv + ReLU.
// = v10 with K-chunk 128 -> 256 (two 128-windows per pass). The per-pass
// latency toll (convoyed loads between barriers) is paid NPASS times;
// halving NPASS (11->6 for lc1) halves it, with 2x compute per pass to
// hide under. LDS 2x32KB dbuf + table -> 70KB -> 2 blocks/CU (2 vs 4
// proven neutral, v6/v10). Raw lgkm-only barrier, int4 offset table,
// XCD swizzle retained. 512 thr = bg(4) x cog(4) x kl(32); acc[8][4].
// Reg budget: acc 32 + wv 16 + tmp 16 + addr ~20 < 128 (no cap, no spill).
// ---------------------------------------------------------------------------
template<int KS, int STRIDE, int HIN, int WIN, int HOUT, int WOUT>
__global__ __launch_bounds__(512) void lc_v11_kernel(
    const float* __restrict__ in, const float* __restrict__ w,
    const float* __restrict__ bias, float* __restrict__ out)
{
    constexpr int K     = 16 * KS * KS;
    constexpr int K2    = KS * KS;
    constexpr int NPASS = (K + 255) / 256;
    constexpr int KPAD  = NPASS * 256;
    constexpr int HW    = HOUT * WOUT;
    constexpr int CHW   = 16 * HIN * WIN;

    __shared__ float patch_s[2][8192];     // 2 x 32b x 256k = 64 KB
    __shared__ int   base_s[KPAD];         // <= 6 KB

    const int tid = threadIdx.x;
    const int pos = xcd_swizzle(blockIdx.x, HW);
    const int oh = pos / WOUT, ow = pos % WOUT;
    const int posoff = (oh * STRIDE) * WIN + ow * STRIDE;

    // position-independent gather-offset table (built once)
    for (int k = tid; k < KPAD; k += 512) {
        int v = 0;
        if (k < K) {
            int ci = k / K2;
            int r  = k - ci * K2;
            int kh = r / KS, kw = r - kh * KS;
            v = ci * (HIN * WIN) + kh * WIN + kw;
        }
        base_s[k] = v;
    }

    const int kl  = tid & 31;
    const int cog = (tid >> 5) & 3;
    const int bg  = tid >> 7;              // 0..3
    const int b0  = bg * 8;

    // staging role: thread stages, per 128-window, float4 for batch sb and sb+16
    const int sb = tid >> 5;               // 0..15
    const int k0 = (tid & 31) * 4;         // k offset within a 128-window
    const float* gsrc0 = in + sb * CHW + posoff;
    const float* gsrc1 = gsrc0 + 16 * CHW;

    const float* wbase = w + (size_t)pos * 16 * K;

    float acc[8][4];
    #pragma unroll
    for (int i = 0; i < 8; ++i)
        #pragma unroll
        for (int j = 0; j < 4; ++j) acc[i][j] = 0.f;

    __syncthreads();                       // table ready (full sync, once)

    // stage one 128-window (kb = window base in k-space) into buf
    auto stage_window = [&](int buf, int kb, int win) {
        int4 off4 = *reinterpret_cast<const int4*>(&base_s[kb + k0]);
        float t0x = gsrc0[off4.x], t0y = gsrc0[off4.y],
              t0z = gsrc0[off4.z], t0w = gsrc0[off4.w];
        float t1x = gsrc1[off4.x], t1y = gsrc1[off4.y],
              t1z = gsrc1[off4.z], t1w = gsrc1[off4.w];
        *reinterpret_cast<float4*>(&patch_s[buf][sb * 256 + win * 128 + k0]) =
            make_float4(t0x, t0y, t0z, t0w);
        *reinterpret_cast<float4*>(&patch_s[buf][(sb + 16) * 256 + win * 128 + k0]) =
            make_float4(t1x, t1y, t1z, t1w);
    };

    {   // prologue: stage pass 0 (both windows)
        stage_window(0, 0, 0);
        stage_window(0, 128, 1);
    }
    asm volatile("s_waitcnt lgkmcnt(0)" ::: "memory");
    __builtin_amdgcn_s_barrier();

    int cur = 0;
    #pragma unroll 1
    for (int ps = 0; ps < NPASS; ++ps) {
        const bool more = (ps + 1 < NPASS);
        const int kb = ps * 256;

        // ---- window A: weights -> regs, compute ----
        {
            float4 wv[4];
            const int kwA = kb + kl * 4;
            #pragma unroll
            for (int cj = 0; cj < 4; ++cj)
                wv[cj] = (kwA < K)
                    ? *reinterpret_cast<const float4*>(wbase + (size_t)(cog * 4 + cj) * K + kwA)
                    : make_float4(0.f, 0.f, 0.f, 0.f);
            #pragma unroll
            for (int bi = 0; bi < 8; ++bi) {
                float4 pv = *reinterpret_cast<const float4*>(
                    &patch_s[cur][(b0 + bi) * 256 + kl * 4]);
                #pragma unroll
                for (int cj = 0; cj < 4; ++cj)
                    acc[bi][cj] += pv.x * wv[cj].x + pv.y * wv[cj].y
                                 + pv.z * wv[cj].z + pv.w * wv[cj].w;
            }
        }
        // ---- next-pass gathers (issued between the two compute windows) ----
        if (more) {
            stage_window(cur ^ 1, kb + 256, 0);
            stage_window(cur ^ 1, kb + 384, 1);
        }
        // ---- window B: weights -> regs, compute ----
        {
            float4 wv[4];
            const int kwB = kb + 128 + kl * 4;
            #pragma unroll
            for (int cj = 0; cj < 4; ++cj)
                wv[cj] = (kwB < K)
                    ? *reinterpret_cast<const float4*>(wbase + (size_t)(cog * 4 + cj) * K + kwB)
                    : make_float4(0.f, 0.f, 0.f, 0.f);
            #pragma unroll
            for (int bi = 0; bi < 8; ++bi) {
                float4 pv = *reinterpret_cast<const float4*>(
                    &patch_s[cur][(b0 + bi) * 256 + 128 + kl * 4]);
                #pragma unroll
                for (int cj = 0; cj < 4; ++cj)
                    acc[bi][cj] += pv.x * wv[cj].x + pv.y * wv[cj].y
                                 + pv.z * wv[cj].z + pv.w * wv[cj].w;
            }
        }
        // LDS-only barrier: ds ops retired (lgkmcnt); global loads may
        // stay outstanding (counted vmcnt at their uses).
        asm volatile("s_waitcnt lgkmcnt(0)" ::: "memory");
        __builtin_amdgcn_s_barrier();
        cur ^= 1;
    }

    // reduce over the 32 kl lanes (masks 1..16 stay within 32-lane halves)
    #pragma unroll
    for (int bi = 0; bi < 8; ++bi)
        #pragma unroll
        for (int cj = 0; cj < 4; ++cj) {
            float v = acc[bi][cj];
            v += __shfl_xor(v, 1);
            v += __shfl_xor(v, 2);
            v += __shfl_xor(v, 4);
            v += __shfl_xor(v, 8);
            v += __shfl_xor(v, 16);
            acc[bi][cj] = v;
        }

    if (kl == 0) {
        float bv[4];
        #pragma unroll
        for (int cj = 0; cj < 4; ++cj)
            bv[cj] = bias[(cog * 4 + cj) * HW + pos];
        #pragma unroll
        for (int bi = 0; bi < 8; ++bi)
            #pragma unroll
            for (int cj = 0; cj < 4; ++cj) {
                int b = b0 + bi, co = cog * 4 + cj;
                out[(b * 16 + co) * HW + pos] = fmaxf(acc[bi][cj] + bv[cj], 0.f);
            }
    }
}

// ---------------------------------------------------------------------------
// Stage 6 v5: FC (32,7056)@(4096,7056)^T, LDS-pipelined (round-8 proven).
// ---------------------------------------------------------------------------
__global__ __launch_bounds__(512) void fc_v5_kernel(
    const float* __restrict__ in, const float* __restrict__ w,
    float* __restrict__ part)
{
    constexpr int K = 7056, KR = 1764;
    constexpr int NPASS = (KR + 127) / 128;   // 14

    __shared__ float patch_s[2][4096];

    const int tid  = threadIdx.x;
    const int oblk = blockIdx.x;              // 0..255
    const int ks   = blockIdx.y;              // 0..3
    const int kbeg = ks * KR, klim = kbeg + KR;

    const int kl  = tid & 31;
    const int cog = (tid >> 5) & 3;
    const int bg  = tid >> 7;
    const int b0  = bg * 8;

    const int sb = tid >> 5;
    const int k0 = (tid & 31) * 4;
    const float* row0 = in + sb * K;
    const float* row1 = row0 + 16 * K;

    const float* wbase = w + (size_t)(oblk * 16) * K;

    auto ld4 = [&](const float* row, int kg) -> float4 {
        return (kg < klim) ? *reinterpret_cast<const float4*>(row + kg)
                           : make_float4(0.f, 0.f, 0.f, 0.f);
    };

    float acc[8][4];
    #pragma unroll
    for (int i = 0; i < 8; ++i)
        #pragma unroll
        for (int j = 0; j < 4; ++j) acc[i][j] = 0.f;

    float4 wv[4], wvn[4];
    float4 t0, t1;

    {   // prologue (pass 0)
        const int kw4 = kbeg + kl * 4;
        #pragma unroll
        for (int cj = 0; cj < 4; ++cj)
            wv[cj] = (kw4 < klim)
                ? *reinterpret_cast<const float4*>(wbase + (size_t)(cog * 4 + cj) * K + kw4)
                : make_float4(0.f, 0.f, 0.f, 0.f);
        t0 = ld4(row0, kbeg + k0);
        t1 = ld4(row1, kbeg + k0);
        *reinterpret_cast<float4*>(&patch_s[0][tid * 4]) = t0;
        *reinterpret_cast<float4*>(&patch_s[0][2048 + tid * 4]) = t1;
    }
    __syncthreads();

    int cur = 0;
    #pragma unroll 1
    for (int ps = 0; ps < NPASS; ++ps) {
        const bool more = (ps + 1 < NPASS);
        if (more) {
            const int kbn = kbeg + (ps + 1) * 128;
            t0 = ld4(row0, kbn + k0);
            t1 = ld4(row1, kbn + k0);
            const int kw4n = kbn + kl * 4;
            #pragma unroll
            for (int cj = 0; cj < 4; ++cj)
                wvn[cj] = (kw4n < klim)
                    ? *reinterpret_cast<const float4*>(wbase + (size_t)(cog * 4 + cj) * K + kw4n)
                    : make_float4(0.f, 0.f, 0.f, 0.f);
        }
        #pragma unroll
        for (int bi = 0; bi < 8; ++bi) {
            float4 pv = *reinterpret_cast<const float4*>(
                &patch_s[cur][(b0 + bi) * 128 + kl * 4]);
            #pragma unroll
            for (int cj = 0; cj < 4; ++cj)
                acc[bi][cj] += pv.x * wv[cj].x + pv.y * wv[cj].y
                             + pv.z * wv[cj].z + pv.w * wv[cj].w;
        }
        if (more) {
            *reinterpret_cast<float4*>(&patch_s[cur ^ 1][tid * 4]) = t0;
            *reinterpret_cast<float4*>(&patch_s[cur ^ 1][2048 + tid * 4]) = t1;
            #pragma unroll
            for (int cj = 0; cj < 4; ++cj) wv[cj] = wvn[cj];
        }
        __syncthreads();
        cur ^= 1;
    }

    #pragma unroll
    for (int bi = 0; bi < 8; ++bi)
        #pragma unroll
        for (int cj = 0; cj < 4; ++cj) {
            float v = acc[bi][cj];
            v += __shfl_xor(v, 1);
            v += __shfl_xor(v, 2);
            v += __shfl_xor(v, 4);
            v += __shfl_xor(v, 8);
            v += __shfl_xor(v, 16);
            acc[bi][cj] = v;
        }

    if (kl == 0) {
        #pragma unroll
        for (int bi = 0; bi < 8; ++bi)
            #pragma unroll
            for (int cj = 0; cj < 4; ++cj)
                part[(size_t)(ks * 32 + b0 + bi) * 4096 + oblk * 16 + cog * 4 + cj] =
                    acc[bi][cj];
    }
}

__global__ __launch_bounds__(256) void fc_reduce_kernel(
    const float* __restrict__ part, const float* __restrict__ bias,
    float* __restrict__ out)
{
    int i4 = blockIdx.x * 256 + threadIdx.x;
    if (i4 >= 32768) return;
    int b = i4 >> 10, o4 = i4 & 1023;
    const size_t stride = (size_t)32 * 4096;
    const float* base = part + (size_t)b * 4096 + o4 * 4;
    float4 s0 = *reinterpret_cast<const float4*>(base);
    float4 s1 = *reinterpret_cast<const float4*>(base + stride);
    float4 s2 = *reinterpret_cast<const float4*>(base + 2 * stride);
    float4 s3 = *reinterpret_cast<const float4*>(base + 3 * stride);
    float4 bv = *reinterpret_cast<const float4*>(bias + o4 * 4);
    float4 r;
    r.x = s0.x + s1.x + s2.x + s3.x + bv.x;
    r.y = s0.y + s1.y + s2.y + s3.y + bv.y;
    r.z = s0.z + s1.z + s2.z + s3.z + bv.z;
    r.w = s0.w + s1.w + s2.w + s3.w + bv.w;
    *reinterpret_cast<float4*>(out + b * 4096 + o4 * 4) = r;
}

// ---------------------------------------------------------------------------
extern "C" void kernel_launch(void* const* d_in, const int* in_sizes, int n_in,
                              void* d_out, int out_size, void* d_ws, size_t ws_size,
                              hipStream_t stream) {
    const float* x    = (const float*)d_in[0];
    const float* c1w  = (const float*)d_in[1];
    const float* c1b  = (const float*)d_in[2];
    const float* c2w  = (const float*)d_in[3];
    const float* c2b  = (const float*)d_in[4];
    const float* lc1w = (const float*)d_in[5];
    const float* lc1b = (const float*)d_in[6];
    const float* lc2w = (const float*)d_in[7];
    const float* lc2b = (const float*)d_in[8];
    const float* lc3w = (const float*)d_in[9];
    const float* lc3b = (const float*)d_in[10];
    const float* fcw  = (const float*)d_in[11];
    const float* fcb  = (const float*)d_in[12];
    float* out = (float*)d_out;

    float* ws  = (float*)d_ws;
    float* h1p = ws;                 // 32*32*71*71 = 5,161,472
    float* h2  = h1p + 5161472;      // 32*16*63*63 = 2,032,128
    float* h3  = h2  + 2032128;      // 32*16*55*55 = 1,548,800
    float* h4  = h3  + 1548800;      // 32*16*25*25 =   320,000
    float* h5  = h4  + 320000;       // 32*16*21*21 =   225,792
    float* fc_part = h1p;            // conv1 output dead by fc time

    conv1_pool_v2_kernel<<<dim3(25, 4, 32), 256, 0, stream>>>(x, c1w, c1b, h1p);
    conv2_kernel<<<dim3(16, 32), 256, 0, stream>>>(h1p, c2w, c2b, h2);
    lc_v11_kernel<9, 1, 63, 63, 55, 55><<<dim3(55 * 55), 512, 0, stream>>>(h2, lc1w, lc1b, h3);
    lc_v11_kernel<7, 2, 55, 55, 25, 25><<<dim3(25 * 25), 512, 0, stream>>>(h3, lc2w, lc2b, h4);
    lc_v11_kernel<5, 1, 25, 25, 21, 21><<<dim3(21 * 21), 512, 0, stream>>>(h4, lc3w, lc3b, h5);
    fc_v5_kernel<<<dim3(256, 4), 512, 0, stream>>>(h5, fcw, fc_part);
    fc_reduce_kernel<<<dim3(128), 256, 0, stream>>>(fc_part, fcb, out);
}

// Round 15
// 821.407 us; speedup vs baseline: 1.1486x; 1.1486x over previous
//
#include <hip/hip_runtime.h>

// Bijective XCD-aware block swizzle (m204 variant; safe for nwg % 8 != 0).
__device__ __forceinline__ int xcd_swizzle(int bid, int nwg) {
    int q = nwg >> 3, r = nwg & 7;
    int xcd = bid & 7, idx = bid >> 3;
    return (xcd < r) ? xcd * (q + 1) + idx
                     : r * (q + 1) + (xcd - r) * q + idx;
}

// ---------------------------------------------------------------------------
// Stage 1 v2: conv1 (11x11, Cin=1, Cout=32) + ReLU + maxpool 3x3 s2 ceil.
// ---------------------------------------------------------------------------
__global__ __launch_bounds__(256, 4) void conv1_pool_v2_kernel(
    const float* __restrict__ x, const float* __restrict__ w,
    const float* __restrict__ bias, float* __restrict__ out)
{
    const int tile = blockIdx.x;          // 0..24
    const int cog  = blockIdx.y;          // 0..3  (8 couts each)
    const int b    = blockIdx.z;          // 0..31
    const int ty = tile / 5, tx = tile % 5;
    const int pr0 = ty * 16, pc0 = tx * 16;   // pooled origin
    const int cr0 = pr0 * 2, cc0 = pc0 * 2;   // conv origin

    __shared__ float in_s[43 * 44];
    __shared__ float w_s[8][121];
    __shared__ float hp_s[33][8][17];

    const int tid = threadIdx.x;

    const float* xb = x + b * 152 * 152;
    for (int i = tid; i < 43 * 44; i += 256) {
        int r = i / 44, c = i - r * 44;
        int ir = cr0 + r, ic = cc0 + c;
        in_s[i] = (ir < 152 && ic < 152) ? xb[ir * 152 + ic] : 0.f;
    }
    for (int i = tid; i < 8 * 121; i += 256) {
        int co = i / 121, k = i - co * 121;
        w_s[co][k] = w[(cog * 8 + co) * 121 + k];
    }
    __syncthreads();

    for (int task = tid; task < 264; task += 256) {
        const int co  = task & 7;
        const int row = task >> 3;
        float hmax[16];
        if (cr0 + row < 142) {
            float acc[33];
            #pragma unroll
            for (int px = 0; px < 33; ++px) acc[px] = 0.f;
            #pragma unroll 1
            for (int kh = 0; kh < 11; ++kh) {
                float4 rq[11];
                #pragma unroll
                for (int j = 0; j < 11; ++j)
                    rq[j] = *reinterpret_cast<const float4*>(
                        &in_s[(row + kh) * 44 + j * 4]);
                const float* rr = reinterpret_cast<const float*>(rq);
                #pragma unroll
                for (int kw = 0; kw < 11; ++kw) {
                    float wv = w_s[co][kh * 11 + kw];
                    #pragma unroll
                    for (int px = 0; px < 33; ++px)
                        acc[px] += rr[px + kw] * wv;
                }
            }
            const float bv = bias[cog * 8 + co];
            #pragma unroll
            for (int px = 0; px < 33; ++px) {
                float v = fmaxf(acc[px] + bv, 0.f);
                acc[px] = (cc0 + px < 142) ? v : 0.f;
            }
            #pragma unroll
            for (int pc = 0; pc < 16; ++pc)
                hmax[pc] = fmaxf(fmaxf(acc[2 * pc], acc[2 * pc + 1]), acc[2 * pc + 2]);
        } else {
            #pragma unroll
            for (int pc = 0; pc < 16; ++pc) hmax[pc] = 0.f;
        }
        #pragma unroll
        for (int pc = 0; pc < 16; ++pc) hp_s[row][co][pc] = hmax[pc];
    }
    __syncthreads();

    for (int t = tid; t < 2048; t += 256) {
        int co = t >> 8, r = t & 255;
        int ppy = r >> 4, ppc = r & 15;
        float v = fmaxf(fmaxf(hp_s[2 * ppy][co][ppc], hp_s[2 * ppy + 1][co][ppc]),
                        hp_s[2 * ppy + 2][co][ppc]);
        int pr = pr0 + ppy, pc = pc0 + ppc;
        if (pr < 71 && pc < 71)
            out[((b * 32 + cog * 8 + co) * 71 + pr) * 71 + pc] = v;
    }
}

// ---------------------------------------------------------------------------
// Stage 2: conv2 (9x9, Cin=32, Cout=16) + ReLU.
// CHANGED: output written with padded row stride 64 (layout [b][co][63][64])
// so lc1's patch rows have block-uniform alignment (sh = ow & 3).
// ---------------------------------------------------------------------------
__global__ __launch_bounds__(256) void conv2_kernel(
    const float* __restrict__ in, const float* __restrict__ w,
    const float* __restrict__ bias, float* __restrict__ out)
{
    const int tile = blockIdx.x;
    const int b = blockIdx.y;
    const int ty = tile / 4, tx = tile % 4;
    const int oh0 = ty * 16, ow0 = tx * 16;

    __shared__ float in_s[4][24][25];
    __shared__ float w_s[16][324];

    const int tid = threadIdx.x;
    const int co = tid / 16;
    const int py = tid % 16;

    float acc[16];
    #pragma unroll
    for (int i = 0; i < 16; ++i) acc[i] = 0.f;

    for (int cc = 0; cc < 8; ++cc) {
        for (int i = tid; i < 4 * 24 * 24; i += 256) {
            int ci = i / 576, r = (i / 24) % 24, c = i % 24;
            int ih = oh0 + r, iw = ow0 + c;
            float v = 0.f;
            if (ih < 71 && iw < 71)
                v = in[((b * 32 + cc * 4 + ci) * 71 + ih) * 71 + iw];
            in_s[ci][r][c] = v;
        }
        for (int i = tid; i < 16 * 324; i += 256) {
            int c2 = i / 324, t = i % 324;
            w_s[c2][t] = w[c2 * 2592 + cc * 324 + t];
        }
        __syncthreads();

        #pragma unroll 1
        for (int ci = 0; ci < 4; ++ci) {
            #pragma unroll 1
            for (int kh = 0; kh < 9; ++kh) {
                float rr[24];
                #pragma unroll
                for (int c = 0; c < 24; ++c) rr[c] = in_s[ci][py + kh][c];
                #pragma unroll
                for (int kw = 0; kw < 9; ++kw) {
                    float wv = w_s[co][ci * 81 + kh * 9 + kw];
                    #pragma unroll
                    for (int px = 0; px < 16; ++px)
                        acc[px] += rr[kw + px] * wv;
                }
            }
        }
        __syncthreads();
    }

    const int oh = oh0 + py;
    if (oh < 63) {
        const float bv = bias[co];
        #pragma unroll
        for (int px = 0; px < 16; ++px) {
            int ow = ow0 + px;
            if (ow < 63)
                out[((b * 16 + co) * 63 + oh) * 64 + ow] = fmaxf(acc[px] + bv, 0.f);
        }
    }
}

// ---------------------------------------------------------------------------
// Stage 3 (lc1) v12: whole-patch-resident, barrier-free compute.
// Block = (position, 16-batch half). 512 thr = bg(4) x cog(4) x kl(32).
// Staging: 2304 row-tasks (16b x 16ci x 9kh); each row = 3 ALIGNED float4
// global loads (W=64-padded h2 makes sh = ow&3 block-uniform) + 9 scalar
// ds_writes to a k-contiguous patch [16][1300] (83 KB, single buffer).
// ONE __syncthreads total. Compute: free-running 10-quad K-loop, weights
// double-buffered in regs, 4 ds_read_b128 + 64 FMA per quad. Weights read
// 2x total (two halves) = 500 MB HBM, overlapped. shfl-reduce over kl.
// ---------------------------------------------------------------------------
__global__ __launch_bounds__(512) void lc1_v12_kernel(
    const float* __restrict__ in, const float* __restrict__ w,
    const float* __restrict__ bias, float* __restrict__ out)
{
    constexpr int K     = 1296;
    constexpr int WPAD  = 64;
    constexpr int PLANE = 63 * WPAD;       // 4032
    constexpr int CHW   = 16 * PLANE;      // 64512
    constexpr int HW    = 55 * 55;
    constexpr int LSTR  = 1300;            // 16B-aligned (1300*4 % 16 == 0)

    __shared__ float patch_s[16 * LSTR];   // 83,200 B

    const int tid  = threadIdx.x;
    const int pos  = xcd_swizzle(blockIdx.x, HW);
    const int half = blockIdx.y;           // 0,1 -> batches 0-15 / 16-31
    const int oh = pos / 55, ow = pos % 55;
    const int sh = ow & 3;                 // block-uniform alignment shift
    const int gbase = oh * WPAD + (ow - sh);

    // ---- staging: rows -> LDS (k-contiguous) ----
    const float* inb = in + half * 16 * CHW;
    for (int t = tid; t < 2304; t += 512) {
        const int b    = t & 15;
        const int rest = t >> 4;           // ci*9 + kh  (0..143)
        const float* src = inb + b * CHW + (rest / 9) * PLANE
                         + gbase + (rest - (rest / 9) * 9) * WPAD;
        float4 f0 = *reinterpret_cast<const float4*>(src);
        float4 f1 = *reinterpret_cast<const float4*>(src + 4);
        float4 f2 = *reinterpret_cast<const float4*>(src + 8);
        const int kb = b * LSTR + rest * 9;   // = b*LSTR + ci*81 + kh*9
        float* p = &patch_s[kb];
        if (sh == 0) {
            p[0]=f0.x; p[1]=f0.y; p[2]=f0.z; p[3]=f0.w;
            p[4]=f1.x; p[5]=f1.y; p[6]=f1.z; p[7]=f1.w; p[8]=f2.x;
        } else if (sh == 1) {
            p[0]=f0.y; p[1]=f0.z; p[2]=f0.w; p[3]=f1.x;
            p[4]=f1.y; p[5]=f1.z; p[6]=f1.w; p[7]=f2.x; p[8]=f2.y;
        } else if (sh == 2) {
            p[0]=f0.z; p[1]=f0.w; p[2]=f1.x; p[3]=f1.y;
            p[4]=f1.z; p[5]=f1.w; p[6]=f2.x; p[7]=f2.y; p[8]=f2.z;
        } else {
            p[0]=f0.w; p[1]=f1.x; p[2]=f1.y; p[3]=f1.z;
            p[4]=f1.w; p[5]=f2.x; p[6]=f2.y; p[7]=f2.z; p[8]=f2.w;
        }
    }
    __syncthreads();                       // the ONLY barrier

    // ---- compute: free-running K-loop ----
    const int kl  = tid & 31;
    const int cog = (tid >> 5) & 3;
    const int bg  = tid >> 7;              // 0..3 -> 4 batches each
    const float* wbase = w + (size_t)pos * 16 * K + (size_t)(cog * 4) * K;

    float acc[4][4];
    #pragma unroll
    for (int i = 0; i < 4; ++i)
        #pragma unroll
        for (int j = 0; j < 4; ++j) acc[i][j] = 0.f;

    float4 wv[4], wvn[4];
    #pragma unroll
    for (int cj = 0; cj < 4; ++cj)
        wv[cj] = *reinterpret_cast<const float4*>(wbase + cj * K + kl * 4);

    #pragma unroll 1
    for (int q = 0; q < 10; ++q) {
        const int kq = q * 128 + kl * 4;
        if (q < 9) {
            #pragma unroll
            for (int cj = 0; cj < 4; ++cj)
                wvn[cj] = *reinterpret_cast<const float4*>(
                    wbase + cj * K + kq + 128);
        }
        #pragma unroll
        for (int bi = 0; bi < 4; ++bi) {
            float4 pv = *reinterpret_cast<const float4*>(
                &patch_s[(bg * 4 + bi) * LSTR + kq]);
            #pragma unroll
            for (int cj = 0; cj < 4; ++cj)
                acc[bi][cj] += pv.x * wv[cj].x + pv.y * wv[cj].y
                             + pv.z * wv[cj].z + pv.w * wv[cj].w;
        }
        if (q < 9) {
            #pragma unroll
            for (int cj = 0; cj < 4; ++cj) wv[cj] = wvn[cj];
        }
    }
    // tail: k = 1280..1295 (4 quads -> kl 0..3)
    if (kl < 4) {
        const int kq = 1280 + kl * 4;
        float4 wt[4];
        #pragma unroll
        for (int cj = 0; cj < 4; ++cj)
            wt[cj] = *reinterpret_cast<const float4*>(wbase + cj * K + kq);
        #pragma unroll
        for (int bi = 0; bi < 4; ++bi) {
            float4 pv = *reinterpret_cast<const float4*>(
                &patch_s[(bg * 4 + bi) * LSTR + kq]);
            #pragma unroll
            for (int cj = 0; cj < 4; ++cj)
                acc[bi][cj] += pv.x * wt[cj].x + pv.y * wt[cj].y
                             + pv.z * wt[cj].z + pv.w * wt[cj].w;
        }
    }

    // reduce over the 32 kl lanes
    #pragma unroll
    for (int bi = 0; bi < 4; ++bi)
        #pragma unroll
        for (int cj = 0; cj < 4; ++cj) {
            float v = acc[bi][cj];
            v += __shfl_xor(v, 1);
            v += __shfl_xor(v, 2);
            v += __shfl_xor(v, 4);
            v += __shfl_xor(v, 8);
            v += __shfl_xor(v, 16);
            acc[bi][cj] = v;
        }

    if (kl == 0) {
        #pragma unroll
        for (int bi = 0; bi < 4; ++bi)
            #pragma unroll
            for (int cj = 0; cj < 4; ++cj) {
                int b  = half * 16 + bg * 4 + bi;
                int co = cog * 4 + cj;
                out[(b * 16 + co) * HW + pos] =
                    fmaxf(acc[bi][cj] + bias[co * HW + pos], 0.f);
            }
    }
}

// ---------------------------------------------------------------------------
// Stages 4-5 (lc2, lc3) v10: proven 333-era template, unchanged.
// ---------------------------------------------------------------------------
template<int KS, int STRIDE, int HIN, int WIN, int HOUT, int WOUT>
__global__ __launch_bounds__(512) void lc_v10_kernel(
    const float* __restrict__ in, const float* __restrict__ w,
    const float* __restrict__ bias, float* __restrict__ out)
{
    constexpr int K     = 16 * KS * KS;
    constexpr int K2    = KS * KS;
    constexpr int NPASS = (K + 127) / 128;
    constexpr int KPAD  = NPASS * 128;
    constexpr int HW    = HOUT * WOUT;
    constexpr int CHW   = 16 * HIN * WIN;

    __shared__ float patch_s[2][4096];
    __shared__ int   base_s[KPAD];

    const int tid = threadIdx.x;
    const int pos = xcd_swizzle(blockIdx.x, HW);
    const int oh = pos / WOUT, ow = pos % WOUT;
    const int posoff = (oh * STRIDE) * WIN + ow * STRIDE;

    for (int k = tid; k < KPAD; k += 512) {
        int v = 0;
        if (k < K) {
            int ci = k / K2;
            int r  = k - ci * K2;
            int kh = r / KS, kw = r - kh * KS;
            v = ci * (HIN * WIN) + kh * WIN + kw;
        }
        base_s[k] = v;
    }

    const int kl  = tid & 31;
    const int cog = (tid >> 5) & 3;
    const int bg  = tid >> 7;
    const int b0  = bg * 8;

    const int sb = tid >> 5;
    const int k0 = (tid & 31) * 4;
    const float* gsrc0 = in + sb * CHW + posoff;
    const float* gsrc1 = gsrc0 + 16 * CHW;

    const float* wbase = w + (size_t)pos * 16 * K;

    float acc[8][4];
    #pragma unroll
    for (int i = 0; i < 8; ++i)
        #pragma unroll
        for (int j = 0; j < 4; ++j) acc[i][j] = 0.f;

    __syncthreads();

    {
        int4 off4 = *reinterpret_cast<const int4*>(&base_s[k0]);
        float t0x = gsrc0[off4.x], t0y = gsrc0[off4.y],
              t0z = gsrc0[off4.z], t0w = gsrc0[off4.w];
        float t1x = gsrc1[off4.x], t1y = gsrc1[off4.y],
              t1z = gsrc1[off4.z], t1w = gsrc1[off4.w];
        *reinterpret_cast<float4*>(&patch_s[0][tid * 4]) =
            make_float4(t0x, t0y, t0z, t0w);
        *reinterpret_cast<float4*>(&patch_s[0][2048 + tid * 4]) =
            make_float4(t1x, t1y, t1z, t1w);
    }
    asm volatile("s_waitcnt lgkmcnt(0)" ::: "memory");
    __builtin_amdgcn_s_barrier();

    int cur = 0;
    #pragma unroll 1
    for (int ps = 0; ps < NPASS; ++ps) {
        const bool more = (ps + 1 < NPASS);
        float4 wv[4];
        {
            const int kw4 = ps * 128 + kl * 4;
            #pragma unroll
            for (int cj = 0; cj < 4; ++cj)
                wv[cj] = (kw4 < K)
                    ? *reinterpret_cast<const float4*>(wbase + (size_t)(cog * 4 + cj) * K + kw4)
                    : make_float4(0.f, 0.f, 0.f, 0.f);
        }
        float t0x, t0y, t0z, t0w, t1x, t1y, t1z, t1w;
        if (more) {
            int4 off4 = *reinterpret_cast<const int4*>(&base_s[(ps + 1) * 128 + k0]);
            t0x = gsrc0[off4.x]; t0y = gsrc0[off4.y];
            t0z = gsrc0[off4.z]; t0w = gsrc0[off4.w];
            t1x = gsrc1[off4.x]; t1y = gsrc1[off4.y];
            t1z = gsrc1[off4.z]; t1w = gsrc1[off4.w];
        }
        #pragma unroll
        for (int bi = 0; bi < 8; ++bi) {
            float4 pv = *reinterpret_cast<const float4*>(
                &patch_s[cur][(b0 + bi) * 128 + kl * 4]);
            #pragma unroll
            for (int cj = 0; cj < 4; ++cj)
                acc[bi][cj] += pv.x * wv[cj].x + pv.y * wv[cj].y
                             + pv.z * wv[cj].z + pv.w * wv[cj].w;
        }
        if (more) {
            *reinterpret_cast<float4*>(&patch_s[cur ^ 1][tid * 4]) =
                make_float4(t0x, t0y, t0z, t0w);
            *reinterpret_cast<float4*>(&patch_s[cur ^ 1][2048 + tid * 4]) =
                make_float4(t1x, t1y, t1z, t1w);
        }
        asm volatile("s_waitcnt lgkmcnt(0)" ::: "memory");
        __builtin_amdgcn_s_barrier();
        cur ^= 1;
    }

    #pragma unroll
    for (int bi = 0; bi < 8; ++bi)
        #pragma unroll
        for (int cj = 0; cj < 4; ++cj) {
            float v = acc[bi][cj];
            v += __shfl_xor(v, 1);
            v += __shfl_xor(v, 2);
            v += __shfl_xor(v, 4);
            v += __shfl_xor(v, 8);
            v += __shfl_xor(v, 16);
            acc[bi][cj] = v;
        }

    if (kl == 0) {
        float bv[4];
        #pragma unroll
        for (int cj = 0; cj < 4; ++cj)
            bv[cj] = bias[(cog * 4 + cj) * HW + pos];
        #pragma unroll
        for (int bi = 0; bi < 8; ++bi)
            #pragma unroll
            for (int cj = 0; cj < 4; ++cj) {
                int b = b0 + bi, co = cog * 4 + cj;
                out[(b * 16 + co) * HW + pos] = fmaxf(acc[bi][cj] + bv[cj], 0.f);
            }
    }
}

// ---------------------------------------------------------------------------
// Stage 6 v5: FC (32,7056)@(4096,7056)^T, LDS-pipelined (round-8 proven).
// ---------------------------------------------------------------------------
__global__ __launch_bounds__(512) void fc_v5_kernel(
    const float* __restrict__ in, const float* __restrict__ w,
    float* __restrict__ part)
{
    constexpr int K = 7056, KR = 1764;
    constexpr int NPASS = (KR + 127) / 128;   // 14

    __shared__ float patch_s[2][4096];

    const int tid  = threadIdx.x;
    const int oblk = blockIdx.x;
    const int ks   = blockIdx.y;
    const int kbeg = ks * KR, klim = kbeg + KR;

    const int kl  = tid & 31;
    const int cog = (tid >> 5) & 3;
    const int bg  = tid >> 7;
    const int b0  = bg * 8;

    const int sb = tid >> 5;
    const int k0 = (tid & 31) * 4;
    const float* row0 = in + sb * K;
    const float* row1 = row0 + 16 * K;

    const float* wbase = w + (size_t)(oblk * 16) * K;

    auto ld4 = [&](const float* row, int kg) -> float4 {
        return (kg < klim) ? *reinterpret_cast<const float4*>(row + kg)
                           : make_float4(0.f, 0.f, 0.f, 0.f);
    };

    float acc[8][4];
    #pragma unroll
    for (int i = 0; i < 8; ++i)
        #pragma unroll
        for (int j = 0; j < 4; ++j) acc[i][j] = 0.f;

    float4 wv[4], wvn[4];
    float4 t0, t1;

    {
        const int kw4 = kbeg + kl * 4;
        #pragma unroll
        for (int cj = 0; cj < 4; ++cj)
            wv[cj] = (kw4 < klim)
                ? *reinterpret_cast<const float4*>(wbase + (size_t)(cog * 4 + cj) * K + kw4)
                : make_float4(0.f, 0.f, 0.f, 0.f);
        t0 = ld4(row0, kbeg + k0);
        t1 = ld4(row1, kbeg + k0);
        *reinterpret_cast<float4*>(&patch_s[0][tid * 4]) = t0;
        *reinterpret_cast<float4*>(&patch_s[0][2048 + tid * 4]) = t1;
    }
    __syncthreads();

    int cur = 0;
    #pragma unroll 1
    for (int ps = 0; ps < NPASS; ++ps) {
        const bool more = (ps + 1 < NPASS);
        if (more) {
            const int kbn = kbeg + (ps + 1) * 128;
            t0 = ld4(row0, kbn + k0);
            t1 = ld4(row1, kbn + k0);
            const int kw4n = kbn + kl * 4;
            #pragma unroll
            for (int cj = 0; cj < 4; ++cj)
                wvn[cj] = (kw4n < klim)
                    ? *reinterpret_cast<const float4*>(wbase + (size_t)(cog * 4 + cj) * K + kw4n)
                    : make_float4(0.f, 0.f, 0.f, 0.f);
        }
        #pragma unroll
        for (int bi = 0; bi < 8; ++bi) {
            float4 pv = *reinterpret_cast<const float4*>(
                &patch_s[cur][(b0 + bi) * 128 + kl * 4]);
            #pragma unroll
            for (int cj = 0; cj < 4; ++cj)
                acc[bi][cj] += pv.x * wv[cj].x + pv.y * wv[cj].y
                             + pv.z * wv[cj].z + pv.w * wv[cj].w;
        }
        if (more) {
            *reinterpret_cast<float4*>(&patch_s[cur ^ 1][tid * 4]) = t0;
            *reinterpret_cast<float4*>(&patch_s[cur ^ 1][2048 + tid * 4]) = t1;
            #pragma unroll
            for (int cj = 0; cj < 4; ++cj) wv[cj] = wvn[cj];
        }
        __syncthreads();
        cur ^= 1;
    }

    #pragma unroll
    for (int bi = 0; bi < 8; ++bi)
        #pragma unroll
        for (int cj = 0; cj < 4; ++cj) {
            float v = acc[bi][cj];
            v += __shfl_xor(v, 1);
            v += __shfl_xor(v, 2);
            v += __shfl_xor(v, 4);
            v += __shfl_xor(v, 8);
            v += __shfl_xor(v, 16);
            acc[bi][cj] = v;
        }

    if (kl == 0) {
        #pragma unroll
        for (int bi = 0; bi < 8; ++bi)
            #pragma unroll
            for (int cj = 0; cj < 4; ++cj)
                part[(size_t)(ks * 32 + b0 + bi) * 4096 + oblk * 16 + cog * 4 + cj] =
                    acc[bi][cj];
    }
}

__global__ __launch_bounds__(256) void fc_reduce_kernel(
    const float* __restrict__ part, const float* __restrict__ bias,
    float* __restrict__ out)
{
    int i4 = blockIdx.x * 256 + threadIdx.x;
    if (i4 >= 32768) return;
    int b = i4 >> 10, o4 = i4 & 1023;
    const size_t stride = (size_t)32 * 4096;
    const float* base = part + (size_t)b * 4096 + o4 * 4;
    float4 s0 = *reinterpret_cast<const float4*>(base);
    float4 s1 = *reinterpret_cast<const float4*>(base + stride);
    float4 s2 = *reinterpret_cast<const float4*>(base + 2 * stride);
    float4 s3 = *reinterpret_cast<const float4*>(base + 3 * stride);
    float4 bv = *reinterpret_cast<const float4*>(bias + o4 * 4);
    float4 r;
    r.x = s0.x + s1.x + s2.x + s3.x + bv.x;
    r.y = s0.y + s1.y + s2.y + s3.y + bv.y;
    r.z = s0.z + s1.z + s2.z + s3.z + bv.z;
    r.w = s0.w + s1.w + s2.w + s3.w + bv.w;
    *reinterpret_cast<float4*>(out + b * 4096 + o4 * 4) = r;
}

// ---------------------------------------------------------------------------
extern "C" void kernel_launch(void* const* d_in, const int* in_sizes, int n_in,
                              void* d_out, int out_size, void* d_ws, size_t ws_size,
                              hipStream_t stream) {
    const float* x    = (const float*)d_in[0];
    const float* c1w  = (const float*)d_in[1];
    const float* c1b  = (const float*)d_in[2];
    const float* c2w  = (const float*)d_in[3];
    const float* c2b  = (const float*)d_in[4];
    const float* lc1w = (const float*)d_in[5];
    const float* lc1b = (const float*)d_in[6];
    const float* lc2w = (const float*)d_in[7];
    const float* lc2b = (const float*)d_in[8];
    const float* lc3w = (const float*)d_in[9];
    const float* lc3b = (const float*)d_in[10];
    const float* fcw  = (const float*)d_in[11];
    const float* fcb  = (const float*)d_in[12];
    float* out = (float*)d_out;

    float* ws  = (float*)d_ws;
    float* h1p = ws;                 // 32*32*71*71 = 5,161,472
    float* h2  = h1p + 5161472;      // padded: 32*16*63*64 = 2,064,384 (+64 pad)
    float* h3  = h2  + 2064448;      // 32*16*55*55 = 1,548,800
    float* h4  = h3  + 1548800;      // 32*16*25*25 =   320,000
    float* h5  = h4  + 320000;       // 32*16*21*21 =   225,792
    float* fc_part = h1p;            // conv1 output dead by fc time

    conv1_pool_v2_kernel<<<dim3(25, 4, 32), 256, 0, stream>>>(x, c1w, c1b, h1p);
    conv2_kernel<<<dim3(16, 32), 256, 0, stream>>>(h1p, c2w, c2b, h2);
    lc1_v12_kernel<<<dim3(55 * 55, 2), 512, 0, stream>>>(h2, lc1w, lc1b, h3);
    lc_v10_kernel<7, 2, 55, 55, 25, 25><<<dim3(25 * 25), 512, 0, stream>>>(h3, lc2w, lc2b, h4);
    lc_v10_kernel<5, 1, 25, 25, 21, 21><<<dim3(21 * 21), 512, 0, stream>>>(h4, lc3w, lc3b, h5);
    fc_v5_kernel<<<dim3(256, 4), 512, 0, stream>>>(h5, fcw, fc_part);
    fc_reduce_kernel<<<dim3(128), 256, 0, stream>>>(fc_part, fcb, out);
}

// Round 16
// 676.168 us; speedup vs baseline: 1.3954x; 1.2148x over previous
//
#include <hip/hip_runtime.h>

typedef __attribute__((ext_vector_type(8))) short bf16x8;
typedef __attribute__((ext_vector_type(4))) float f32x4;

// Bijective XCD-aware block swizzle (m204 variant; safe for nwg % 8 != 0).
__device__ __forceinline__ int xcd_swizzle(int bid, int nwg) {
    int q = nwg >> 3, r = nwg & 7;
    int xcd = bid & 7, idx = bid >> 3;
    return (xcd < r) ? xcd * (q + 1) + idx
                     : r * (q + 1) + (xcd - r) * q + idx;
}

// split fp32 -> bf16 hi + bf16 lo  (hi = truncated top16; lo = bf16(f - hi))
__device__ __forceinline__ void split_bf16(const float* v, bf16x8& hi, bf16x8& lo) {
    #pragma unroll
    for (int j = 0; j < 8; ++j) {
        unsigned u = __float_as_uint(v[j]);
        unsigned h = u >> 16;
        hi[j] = (short)h;
        float hf = __uint_as_float(h << 16);
        float lf = v[j] - hf;
        lo[j] = (short)(__float_as_uint(lf) >> 16);
    }
}

// ---------------------------------------------------------------------------
// Stage 1 v2: conv1 (11x11, Cin=1, Cout=32) + ReLU + maxpool 3x3 s2 ceil.
// ---------------------------------------------------------------------------
__global__ __launch_bounds__(256, 4) void conv1_pool_v2_kernel(
    const float* __restrict__ x, const float* __restrict__ w,
    const float* __restrict__ bias, float* __restrict__ out)
{
    const int tile = blockIdx.x;          // 0..24
    const int cog  = blockIdx.y;          // 0..3  (8 couts each)
    const int b    = blockIdx.z;          // 0..31
    const int ty = tile / 5, tx = tile % 5;
    const int pr0 = ty * 16, pc0 = tx * 16;
    const int cr0 = pr0 * 2, cc0 = pc0 * 2;

    __shared__ float in_s[43 * 44];
    __shared__ float w_s[8][121];
    __shared__ float hp_s[33][8][17];

    const int tid = threadIdx.x;

    const float* xb = x + b * 152 * 152;
    for (int i = tid; i < 43 * 44; i += 256) {
        int r = i / 44, c = i - r * 44;
        int ir = cr0 + r, ic = cc0 + c;
        in_s[i] = (ir < 152 && ic < 152) ? xb[ir * 152 + ic] : 0.f;
    }
    for (int i = tid; i < 8 * 121; i += 256) {
        int co = i / 121, k = i - co * 121;
        w_s[co][k] = w[(cog * 8 + co) * 121 + k];
    }
    __syncthreads();

    for (int task = tid; task < 264; task += 256) {
        const int co  = task & 7;
        const int row = task >> 3;
        float hmax[16];
        if (cr0 + row < 142) {
            float acc[33];
            #pragma unroll
            for (int px = 0; px < 33; ++px) acc[px] = 0.f;
            #pragma unroll 1
            for (int kh = 0; kh < 11; ++kh) {
                float4 rq[11];
                #pragma unroll
                for (int j = 0; j < 11; ++j)
                    rq[j] = *reinterpret_cast<const float4*>(
                        &in_s[(row + kh) * 44 + j * 4]);
                const float* rr = reinterpret_cast<const float*>(rq);
                #pragma unroll
                for (int kw = 0; kw < 11; ++kw) {
                    float wv = w_s[co][kh * 11 + kw];
                    #pragma unroll
                    for (int px = 0; px < 33; ++px)
                        acc[px] += rr[px + kw] * wv;
                }
            }
            const float bv = bias[cog * 8 + co];
            #pragma unroll
            for (int px = 0; px < 33; ++px) {
                float v = fmaxf(acc[px] + bv, 0.f);
                acc[px] = (cc0 + px < 142) ? v : 0.f;
            }
            #pragma unroll
            for (int pc = 0; pc < 16; ++pc)
                hmax[pc] = fmaxf(fmaxf(acc[2 * pc], acc[2 * pc + 1]), acc[2 * pc + 2]);
        } else {
            #pragma unroll
            for (int pc = 0; pc < 16; ++pc) hmax[pc] = 0.f;
        }
        #pragma unroll
        for (int pc = 0; pc < 16; ++pc) hp_s[row][co][pc] = hmax[pc];
    }
    __syncthreads();

    for (int t = tid; t < 2048; t += 256) {
        int co = t >> 8, r = t & 255;
        int ppy = r >> 4, ppc = r & 15;
        float v = fmaxf(fmaxf(hp_s[2 * ppy][co][ppc], hp_s[2 * ppy + 1][co][ppc]),
                        hp_s[2 * ppy + 2][co][ppc]);
        int pr = pr0 + ppy, pc = pc0 + ppc;
        if (pr < 71 && pc < 71)
            out[((b * 32 + cog * 8 + co) * 71 + pr) * 71 + pc] = v;
    }
}

// ---------------------------------------------------------------------------
// Stage 2: conv2 (9x9, Cin=32, Cout=16) + ReLU. Output row stride 64 (padded)
// so lc1's patch rows have block-uniform alignment.
// ---------------------------------------------------------------------------
__global__ __launch_bounds__(256) void conv2_kernel(
    const float* __restrict__ in, const float* __restrict__ w,
    const float* __restrict__ bias, float* __restrict__ out)
{
    const int tile = blockIdx.x;
    const int b = blockIdx.y;
    const int ty = tile / 4, tx = tile % 4;
    const int oh0 = ty * 16, ow0 = tx * 16;

    __shared__ float in_s[4][24][25];
    __shared__ float w_s[16][324];

    const int tid = threadIdx.x;
    const int co = tid / 16;
    const int py = tid % 16;

    float acc[16];
    #pragma unroll
    for (int i = 0; i < 16; ++i) acc[i] = 0.f;

    for (int cc = 0; cc < 8; ++cc) {
        for (int i = tid; i < 4 * 24 * 24; i += 256) {
            int ci = i / 576, r = (i / 24) % 24, c = i % 24;
            int ih = oh0 + r, iw = ow0 + c;
            float v = 0.f;
            if (ih < 71 && iw < 71)
                v = in[((b * 32 + cc * 4 + ci) * 71 + ih) * 71 + iw];
            in_s[ci][r][c] = v;
        }
        for (int i = tid; i < 16 * 324; i += 256) {
            int c2 = i / 324, t = i % 324;
            w_s[c2][t] = w[c2 * 2592 + cc * 324 + t];
        }
        __syncthreads();

        #pragma unroll 1
        for (int ci = 0; ci < 4; ++ci) {
            #pragma unroll 1
            for (int kh = 0; kh < 9; ++kh) {
                float rr[24];
                #pragma unroll
                for (int c = 0; c < 24; ++c) rr[c] = in_s[ci][py + kh][c];
                #pragma unroll
                for (int kw = 0; kw < 9; ++kw) {
                    float wv = w_s[co][ci * 81 + kh * 9 + kw];
                    #pragma unroll
                    for (int px = 0; px < 16; ++px)
                        acc[px] += rr[kw + px] * wv;
                }
            }
        }
        __syncthreads();
    }

    const int oh = oh0 + py;
    if (oh < 63) {
        const float bv = bias[co];
        #pragma unroll
        for (int px = 0; px < 16; ++px) {
            int ow = ow0 + px;
            if (ow < 63)
                out[((b * 16 + co) * 63 + oh) * 64 + ow] = fmaxf(acc[px] + bv, 0.f);
        }
    }
}

// ---------------------------------------------------------------------------
// Stage 3 (lc1) v13: MFMA bf16x3 (fp32-accurate split: hi*hi + hi*lo + lo*hi).
// Per position: C[32,16] = patch[32,1296] . W^T  ->  2 half-blocks of one
// 16x16 M-tile each. Block = (pos, half), 512 thr = 8 waves, split-K over
// 41 ksteps of 32. Patch staged fp32 into LDS once (v12's proven vectorized
// row staging); weight fragments read once from global (no redundancy:
// B-frag spans all 16 co). Fragment layouts (CDNA std / m89-verified C/D):
//   A: m=lane&15, k=(lane>>4)*8+j   B: n=lane&15, same k
//   D: col=lane&15, row=(lane>>4)*4+reg
// Split-K partials reduced through LDS; bias+relu on store.
// ---------------------------------------------------------------------------
__global__ __launch_bounds__(512) void lc1_mfma_kernel(
    const float* __restrict__ in, const float* __restrict__ w,
    const float* __restrict__ bias, float* __restrict__ out)
{
    constexpr int K     = 1296;
    constexpr int WPAD  = 64;
    constexpr int PLANE = 63 * WPAD;       // 4032
    constexpr int CHW   = 16 * PLANE;      // 64512
    constexpr int HW    = 55 * 55;
    constexpr int LSTR  = 1316;            // pad: 1316 % 32 = 4 -> banks rotate

    __shared__ float patch_f[16 * LSTR];   // 84,224 B
    __shared__ float red[8 * 256];         //  8,192 B

    const int tid = threadIdx.x;
    const int sb2 = xcd_swizzle(blockIdx.x, 2 * HW);
    const int pos = sb2 >> 1;
    const int half = sb2 & 1;
    const int oh = pos / 55, ow = pos % 55;
    const int sh = ow & 3;                 // block-uniform alignment shift
    const int gbase = oh * WPAD + (ow - sh);

    // ---- stage patch rows -> LDS (fp32, k-contiguous), proven in v12 ----
    const float* inb = in + half * 16 * CHW;
    for (int t = tid; t < 2304; t += 512) {
        const int b    = t & 15;
        const int rest = t >> 4;           // ci*9 + kh  (0..143)
        const float* src = inb + b * CHW + (rest / 9) * PLANE
                         + gbase + (rest - (rest / 9) * 9) * WPAD;
        float4 f0 = *reinterpret_cast<const float4*>(src);
        float4 f1 = *reinterpret_cast<const float4*>(src + 4);
        float4 f2 = *reinterpret_cast<const float4*>(src + 8);
        float* p = &patch_f[b * LSTR + rest * 9];
        if (sh == 0) {
            p[0]=f0.x; p[1]=f0.y; p[2]=f0.z; p[3]=f0.w;
            p[4]=f1.x; p[5]=f1.y; p[6]=f1.z; p[7]=f1.w; p[8]=f2.x;
        } else if (sh == 1) {
            p[0]=f0.y; p[1]=f0.z; p[2]=f0.w; p[3]=f1.x;
            p[4]=f1.y; p[5]=f1.z; p[6]=f1.w; p[7]=f2.x; p[8]=f2.y;
        } else if (sh == 2) {
            p[0]=f0.z; p[1]=f0.w; p[2]=f1.x; p[3]=f1.y;
            p[4]=f1.z; p[5]=f1.w; p[6]=f2.x; p[7]=f2.y; p[8]=f2.z;
        } else {
            p[0]=f0.w; p[1]=f1.x; p[2]=f1.y; p[3]=f1.z;
            p[4]=f1.w; p[5]=f2.x; p[6]=f2.y; p[7]=f2.z; p[8]=f2.w;
        }
    }
    // zero k-tail 1296..1315 (covers padded ksteps)
    for (int i = tid; i < 16 * 20; i += 512)
        patch_f[(i / 20) * LSTR + 1296 + (i % 20)] = 0.f;
    __syncthreads();

    // ---- split-K MFMA compute ----
    const int wid  = tid >> 6;             // wave 0..7
    const int lane = tid & 63;
    const int bq = lane & 15;              // A row (b) / B col (co)
    const int kq = lane >> 4;              // 0..3 -> k-run (kq*8)

    f32x4 acc = {0.f, 0.f, 0.f, 0.f};
    const float* wpos = w + (size_t)pos * 16 * K + (size_t)bq * K;

    #pragma unroll 1
    for (int s = wid; s < 41; s += 8) {
        const int k8 = s * 32 + kq * 8;
        // A fragment from LDS (zero-padded past K)
        float av[8];
        const float* ap = &patch_f[bq * LSTR + k8];
        *reinterpret_cast<float4*>(&av[0]) = *reinterpret_cast<const float4*>(ap);
        *reinterpret_cast<float4*>(&av[4]) = *reinterpret_cast<const float4*>(ap + 4);
        bf16x8 ah, al;
        split_bf16(av, ah, al);
        // B fragment from global (mask past K; runs are 8-aligned, K%8==0)
        float wv[8];
        if (k8 < K) {
            *reinterpret_cast<float4*>(&wv[0]) =
                *reinterpret_cast<const float4*>(wpos + k8);
            *reinterpret_cast<float4*>(&wv[4]) =
                *reinterpret_cast<const float4*>(wpos + k8 + 4);
        } else {
            #pragma unroll
            for (int j = 0; j < 8; ++j) wv[j] = 0.f;
        }
        bf16x8 bh, bl;
        split_bf16(wv, bh, bl);

        acc = __builtin_amdgcn_mfma_f32_16x16x32_bf16(ah, bh, acc, 0, 0, 0);
        acc = __builtin_amdgcn_mfma_f32_16x16x32_bf16(ah, bl, acc, 0, 0, 0);
        acc = __builtin_amdgcn_mfma_f32_16x16x32_bf16(al, bh, acc, 0, 0, 0);
    }

    // ---- split-K reduce through LDS ----
    *reinterpret_cast<float4*>(&red[(wid * 64 + lane) * 4]) =
        make_float4(acc[0], acc[1], acc[2], acc[3]);
    __syncthreads();

    if (tid < 256) {
        const int L = tid & 63, r = tid >> 6;
        float s = 0.f;
        #pragma unroll
        for (int wv2 = 0; wv2 < 8; ++wv2)
            s += red[wv2 * 256 + L * 4 + r];
        const int row = (L >> 4) * 4 + r;      // m89-verified C/D mapping
        const int col = L & 15;
        const int b  = half * 16 + row;
        out[(b * 16 + col) * HW + pos] = fmaxf(s + bias[col * HW + pos], 0.f);
    }
}

// ---------------------------------------------------------------------------
// Stages 4-5 (lc2, lc3) v10: proven template, unchanged.
// ---------------------------------------------------------------------------
template<int KS, int STRIDE, int HIN, int WIN, int HOUT, int WOUT>
__global__ __launch_bounds__(512) void lc_v10_kernel(
    const float* __restrict__ in, const float* __restrict__ w,
    const float* __restrict__ bias, float* __restrict__ out)
{
    constexpr int K     = 16 * KS * KS;
    constexpr int K2    = KS * KS;
    constexpr int NPASS = (K + 127) / 128;
    constexpr int KPAD  = NPASS * 128;
    constexpr int HW    = HOUT * WOUT;
    constexpr int CHW   = 16 * HIN * WIN;

    __shared__ float patch_s[2][4096];
    __shared__ int   base_s[KPAD];

    const int tid = threadIdx.x;
    const int pos = xcd_swizzle(blockIdx.x, HW);
    const int oh = pos / WOUT, ow = pos % WOUT;
    const int posoff = (oh * STRIDE) * WIN + ow * STRIDE;

    for (int k = tid; k < KPAD; k += 512) {
        int v = 0;
        if (k < K) {
            int ci = k / K2;
            int r  = k - ci * K2;
            int kh = r / KS, kw = r - kh * KS;
            v = ci * (HIN * WIN) + kh * WIN + kw;
        }
        base_s[k] = v;
    }

    const int kl  = tid & 31;
    const int cog = (tid >> 5) & 3;
    const int bg  = tid >> 7;
    const int b0  = bg * 8;

    const int sb = tid >> 5;
    const int k0 = (tid & 31) * 4;
    const float* gsrc0 = in + sb * CHW + posoff;
    const float* gsrc1 = gsrc0 + 16 * CHW;

    const float* wbase = w + (size_t)pos * 16 * K;

    float acc[8][4];
    #pragma unroll
    for (int i = 0; i < 8; ++i)
        #pragma unroll
        for (int j = 0; j < 4; ++j) acc[i][j] = 0.f;

    __syncthreads();

    {
        int4 off4 = *reinterpret_cast<const int4*>(&base_s[k0]);
        float t0x = gsrc0[off4.x], t0y = gsrc0[off4.y],
              t0z = gsrc0[off4.z], t0w = gsrc0[off4.w];
        float t1x = gsrc1[off4.x], t1y = gsrc1[off4.y],
              t1z = gsrc1[off4.z], t1w = gsrc1[off4.w];
        *reinterpret_cast<float4*>(&patch_s[0][tid * 4]) =
            make_float4(t0x, t0y, t0z, t0w);
        *reinterpret_cast<float4*>(&patch_s[0][2048 + tid * 4]) =
            make_float4(t1x, t1y, t1z, t1w);
    }
    asm volatile("s_waitcnt lgkmcnt(0)" ::: "memory");
    __builtin_amdgcn_s_barrier();

    int cur = 0;
    #pragma unroll 1
    for (int ps = 0; ps < NPASS; ++ps) {
        const bool more = (ps + 1 < NPASS);
        float4 wv[4];
        {
            const int kw4 = ps * 128 + kl * 4;
            #pragma unroll
            for (int cj = 0; cj < 4; ++cj)
                wv[cj] = (kw4 < K)
                    ? *reinterpret_cast<const float4*>(wbase + (size_t)(cog * 4 + cj) * K + kw4)
                    : make_float4(0.f, 0.f, 0.f, 0.f);
        }
        float t0x, t0y, t0z, t0w, t1x, t1y, t1z, t1w;
        if (more) {
            int4 off4 = *reinterpret_cast<const int4*>(&base_s[(ps + 1) * 128 + k0]);
            t0x = gsrc0[off4.x]; t0y = gsrc0[off4.y];
            t0z = gsrc0[off4.z]; t0w = gsrc0[off4.w];
            t1x = gsrc1[off4.x]; t1y = gsrc1[off4.y];
            t1z = gsrc1[off4.z]; t1w = gsrc1[off4.w];
        }
        #pragma unroll
        for (int bi = 0; bi < 8; ++bi) {
            float4 pv = *reinterpret_cast<const float4*>(
                &patch_s[cur][(b0 + bi) * 128 + kl * 4]);
            #pragma unroll
            for (int cj = 0; cj < 4; ++cj)
                acc[bi][cj] += pv.x * wv[cj].x + pv.y * wv[cj].y
                             + pv.z * wv[cj].z + pv.w * wv[cj].w;
        }
        if (more) {
            *reinterpret_cast<float4*>(&patch_s[cur ^ 1][tid * 4]) =
                make_float4(t0x, t0y, t0z, t0w);
            *reinterpret_cast<float4*>(&patch_s[cur ^ 1][2048 + tid * 4]) =
                make_float4(t1x, t1y, t1z, t1w);
        }
        asm volatile("s_waitcnt lgkmcnt(0)" ::: "memory");
        __builtin_amdgcn_s_barrier();
        cur ^= 1;
    }

    #pragma unroll
    for (int bi = 0; bi < 8; ++bi)
        #pragma unroll
        for (int cj = 0; cj < 4; ++cj) {
            float v = acc[bi][cj];
            v += __shfl_xor(v, 1);
            v += __shfl_xor(v, 2);
            v += __shfl_xor(v, 4);
            v += __shfl_xor(v, 8);
            v += __shfl_xor(v, 16);
            acc[bi][cj] = v;
        }

    if (kl == 0) {
        float bv[4];
        #pragma unroll
        for (int cj = 0; cj < 4; ++cj)
            bv[cj] = bias[(cog * 4 + cj) * HW + pos];
        #pragma unroll
        for (int bi = 0; bi < 8; ++bi)
            #pragma unroll
            for (int cj = 0; cj < 4; ++cj) {
                int b = b0 + bi, co = cog * 4 + cj;
                out[(b * 16 + co) * HW + pos] = fmaxf(acc[bi][cj] + bv[cj], 0.f);
            }
    }
}

// ---------------------------------------------------------------------------
// Stage 6 v5: FC (32,7056)@(4096,7056)^T, LDS-pipelined (round-8 proven).
// ---------------------------------------------------------------------------
__global__ __launch_bounds__(512) void fc_v5_kernel(
    const float* __restrict__ in, const float* __restrict__ w,
    float* __restrict__ part)
{
    constexpr int K = 7056, KR = 1764;
    constexpr int NPASS = (KR + 127) / 128;   // 14

    __shared__ float patch_s[2][4096];

    const int tid  = threadIdx.x;
    const int oblk = blockIdx.x;
    const int ks   = blockIdx.y;
    const int kbeg = ks * KR, klim = kbeg + KR;

    const int kl  = tid & 31;
    const int cog = (tid >> 5) & 3;
    const int bg  = tid >> 7;
    const int b0  = bg * 8;

    const int sb = tid >> 5;
    const int k0 = (tid & 31) * 4;
    const float* row0 = in + sb * K;
    const float* row1 = row0 + 16 * K;

    const float* wbase = w + (size_t)(oblk * 16) * K;

    auto ld4 = [&](const float* row, int kg) -> float4 {
        return (kg < klim) ? *reinterpret_cast<const float4*>(row + kg)
                           : make_float4(0.f, 0.f, 0.f, 0.f);
    };

    float acc[8][4];
    #pragma unroll
    for (int i = 0; i < 8; ++i)
        #pragma unroll
        for (int j = 0; j < 4; ++j) acc[i][j] = 0.f;

    float4 wv[4], wvn[4];
    float4 t0, t1;

    {
        const int kw4 = kbeg + kl * 4;
        #pragma unroll
        for (int cj = 0; cj < 4; ++cj)
            wv[cj] = (kw4 < klim)
                ? *reinterpret_cast<const float4*>(wbase + (size_t)(cog * 4 + cj) * K + kw4)
                : make_float4(0.f, 0.f, 0.f, 0.f);
        t0 = ld4(row0, kbeg + k0);
        t1 = ld4(row1, kbeg + k0);
        *reinterpret_cast<float4*>(&patch_s[0][tid * 4]) = t0;
        *reinterpret_cast<float4*>(&patch_s[0][2048 + tid * 4]) = t1;
    }
    __syncthreads();

    int cur = 0;
    #pragma unroll 1
    for (int ps = 0; ps < NPASS; ++ps) {
        const bool more = (ps + 1 < NPASS);
        if (more) {
            const int kbn = kbeg + (ps + 1) * 128;
            t0 = ld4(row0, kbn + k0);
            t1 = ld4(row1, kbn + k0);
            const int kw4n = kbn + kl * 4;
            #pragma unroll
            for (int cj = 0; cj < 4; ++cj)
                wvn[cj] = (kw4n < klim)
                    ? *reinterpret_cast<const float4*>(wbase + (size_t)(cog * 4 + cj) * K + kw4n)
                    : make_float4(0.f, 0.f, 0.f, 0.f);
        }
        #pragma unroll
        for (int bi = 0; bi < 8; ++bi) {
            float4 pv = *reinterpret_cast<const float4*>(
                &patch_s[cur][(b0 + bi) * 128 + kl * 4]);
            #pragma unroll
            for (int cj = 0; cj < 4; ++cj)
                acc[bi][cj] += pv.x * wv[cj].x + pv.y * wv[cj].y
                             + pv.z * wv[cj].z + pv.w * wv[cj].w;
        }
        if (more) {
            *reinterpret_cast<float4*>(&patch_s[cur ^ 1][tid * 4]) = t0;
            *reinterpret_cast<float4*>(&patch_s[cur ^ 1][2048 + tid * 4]) = t1;
            #pragma unroll
            for (int cj = 0; cj < 4; ++cj) wv[cj] = wvn[cj];
        }
        __syncthreads();
        cur ^= 1;
    }

    #pragma unroll
    for (int bi = 0; bi < 8; ++bi)
        #pragma unroll
        for (int cj = 0; cj < 4; ++cj) {
            float v = acc[bi][cj];
            v += __shfl_xor(v, 1);
            v += __shfl_xor(v, 2);
            v += __shfl_xor(v, 4);
            v += __shfl_xor(v, 8);
            v += __shfl_xor(v, 16);
            acc[bi][cj] = v;
        }

    if (kl == 0) {
        #pragma unroll
        for (int bi = 0; bi < 8; ++bi)
            #pragma unroll
            for (int cj = 0; cj < 4; ++cj)
                part[(size_t)(ks * 32 + b0 + bi) * 4096 + oblk * 16 + cog * 4 + cj] =
                    acc[bi][cj];
    }
}

__global__ __launch_bounds__(256) void fc_reduce_kernel(
    const float* __restrict__ part, const float* __restrict__ bias,
    float* __restrict__ out)
{
    int i4 = blockIdx.x * 256 + threadIdx.x;
    if (i4 >= 32768) return;
    int b = i4 >> 10, o4 = i4 & 1023;
    const size_t stride = (size_t)32 * 4096;
    const float* base = part + (size_t)b * 4096 + o4 * 4;
    float4 s0 = *reinterpret_cast<const float4*>(base);
    float4 s1 = *reinterpret_cast<const float4*>(base + stride);
    float4 s2 = *reinterpret_cast<const float4*>(base + 2 * stride);
    float4 s3 = *reinterpret_cast<const float4*>(base + 3 * stride);
    float4 bv = *reinterpret_cast<const float4*>(bias + o4 * 4);
    float4 r;
    r.x = s0.x + s1.x + s2.x + s3.x + bv.x;
    r.y = s0.y + s1.y + s2.y + s3.y + bv.y;
    r.z = s0.z + s1.z + s2.z + s3.z + bv.z;
    r.w = s0.w + s1.w + s2.w + s3.w + bv.w;
    *reinterpret_cast<float4*>(out + b * 4096 + o4 * 4) = r;
}

// ---------------------------------------------------------------------------
extern "C" void kernel_launch(void* const* d_in, const int* in_sizes, int n_in,
                              void* d_out, int out_size, void* d_ws, size_t ws_size,
                              hipStream_t stream) {
    const float* x    = (const float*)d_in[0];
    const float* c1w  = (const float*)d_in[1];
    const float* c1b  = (const float*)d_in[2];
    const float* c2w  = (const float*)d_in[3];
    const float* c2b  = (const float*)d_in[4];
    const float* lc1w = (const float*)d_in[5];
    const float* lc1b = (const float*)d_in[6];
    const float* lc2w = (const float*)d_in[7];
    const float* lc2b = (const float*)d_in[8];
    const float* lc3w = (const float*)d_in[9];
    const float* lc3b = (const float*)d_in[10];
    const float* fcw  = (const float*)d_in[11];
    const float* fcb  = (const float*)d_in[12];
    float* out = (float*)d_out;

    float* ws  = (float*)d_ws;
    float* h1p = ws;                 // 32*32*71*71 = 5,161,472
    float* h2  = h1p + 5161472;      // padded: 32*16*63*64 = 2,064,384 (+64 pad)
    float* h3  = h2  + 2064448;      // 32*16*55*55 = 1,548,800
    float* h4  = h3  + 1548800;      // 32*16*25*25 =   320,000
    float* h5  = h4  + 320000;       // 32*16*21*21 =   225,792
    float* fc_part = h1p;            // conv1 output dead by fc time

    conv1_pool_v2_kernel<<<dim3(25, 4, 32), 256, 0, stream>>>(x, c1w, c1b, h1p);
    conv2_kernel<<<dim3(16, 32), 256, 0, stream>>>(h1p, c2w, c2b, h2);
    lc1_mfma_kernel<<<dim3(55 * 55 * 2), 512, 0, stream>>>(h2, lc1w, lc1b, h3);
    lc_v10_kernel<7, 2, 55, 55, 25, 25><<<dim3(25 * 25), 512, 0, stream>>>(h3, lc2w, lc2b, h4);
    lc_v10_kernel<5, 1, 25, 25, 21, 21><<<dim3(21 * 21), 512, 0, stream>>>(h4, lc3w, lc3b, h5);
    fc_v5_kernel<<<dim3(256, 4), 512, 0, stream>>>(h5, fcw, fc_part);
    fc_reduce_kernel<<<dim3(128), 256, 0, stream>>>(fc_part, fcb, out);
}

// Round 17
// 650.568 us; speedup vs baseline: 1.4503x; 1.0394x over previous
//
#include <hip/hip_runtime.h>

typedef __attribute__((ext_vector_type(8))) short bf16x8;
typedef __attribute__((ext_vector_type(4))) float f32x4;

// Bijective XCD-aware block swizzle (m204 variant; safe for nwg % 8 != 0).
__device__ __forceinline__ int xcd_swizzle(int bid, int nwg) {
    int q = nwg >> 3, r = nwg & 7;
    int xcd = bid & 7, idx = bid >> 3;
    return (xcd < r) ? xcd * (q + 1) + idx
                     : r * (q + 1) + (xcd - r) * q + idx;
}

// split fp32 -> bf16 hi + bf16 lo  (hi = truncated top16; lo = bf16(f - hi))
__device__ __forceinline__ void split_bf16(const float* v, bf16x8& hi, bf16x8& lo) {
    #pragma unroll
    for (int j = 0; j < 8; ++j) {
        unsigned u = __float_as_uint(v[j]);
        unsigned h = u >> 16;
        hi[j] = (short)h;
        float hf = __uint_as_float(h << 16);
        float lf = v[j] - hf;
        lo[j] = (short)(__float_as_uint(lf) >> 16);
    }
}

// ---------------------------------------------------------------------------
// Stage 1 v2: conv1 (11x11, Cin=1, Cout=32) + ReLU + maxpool 3x3 s2 ceil.
// ---------------------------------------------------------------------------
__global__ __launch_bounds__(256, 4) void conv1_pool_v2_kernel(
    const float* __restrict__ x, const float* __restrict__ w,
    const float* __restrict__ bias, float* __restrict__ out)
{
    const int tile = blockIdx.x;          // 0..24
    const int cog  = blockIdx.y;          // 0..3  (8 couts each)
    const int b    = blockIdx.z;          // 0..31
    const int ty = tile / 5, tx = tile % 5;
    const int pr0 = ty * 16, pc0 = tx * 16;
    const int cr0 = pr0 * 2, cc0 = pc0 * 2;

    __shared__ float in_s[43 * 44];
    __shared__ float w_s[8][121];
    __shared__ float hp_s[33][8][17];

    const int tid = threadIdx.x;

    const float* xb = x + b * 152 * 152;
    for (int i = tid; i < 43 * 44; i += 256) {
        int r = i / 44, c = i - r * 44;
        int ir = cr0 + r, ic = cc0 + c;
        in_s[i] = (ir < 152 && ic < 152) ? xb[ir * 152 + ic] : 0.f;
    }
    for (int i = tid; i < 8 * 121; i += 256) {
        int co = i / 121, k = i - co * 121;
        w_s[co][k] = w[(cog * 8 + co) * 121 + k];
    }
    __syncthreads();

    for (int task = tid; task < 264; task += 256) {
        const int co  = task & 7;
        const int row = task >> 3;
        float hmax[16];
        if (cr0 + row < 142) {
            float acc[33];
            #pragma unroll
            for (int px = 0; px < 33; ++px) acc[px] = 0.f;
            #pragma unroll 1
            for (int kh = 0; kh < 11; ++kh) {
                float4 rq[11];
                #pragma unroll
                for (int j = 0; j < 11; ++j)
                    rq[j] = *reinterpret_cast<const float4*>(
                        &in_s[(row + kh) * 44 + j * 4]);
                const float* rr = reinterpret_cast<const float*>(rq);
                #pragma unroll
                for (int kw = 0; kw < 11; ++kw) {
                    float wv = w_s[co][kh * 11 + kw];
                    #pragma unroll
                    for (int px = 0; px < 33; ++px)
                        acc[px] += rr[px + kw] * wv;
                }
            }
            const float bv = bias[cog * 8 + co];
            #pragma unroll
            for (int px = 0; px < 33; ++px) {
                float v = fmaxf(acc[px] + bv, 0.f);
                acc[px] = (cc0 + px < 142) ? v : 0.f;
            }
            #pragma unroll
            for (int pc = 0; pc < 16; ++pc)
                hmax[pc] = fmaxf(fmaxf(acc[2 * pc], acc[2 * pc + 1]), acc[2 * pc + 2]);
        } else {
            #pragma unroll
            for (int pc = 0; pc < 16; ++pc) hmax[pc] = 0.f;
        }
        #pragma unroll
        for (int pc = 0; pc < 16; ++pc) hp_s[row][co][pc] = hmax[pc];
    }
    __syncthreads();

    for (int t = tid; t < 2048; t += 256) {
        int co = t >> 8, r = t & 255;
        int ppy = r >> 4, ppc = r & 15;
        float v = fmaxf(fmaxf(hp_s[2 * ppy][co][ppc], hp_s[2 * ppy + 1][co][ppc]),
                        hp_s[2 * ppy + 2][co][ppc]);
        int pr = pr0 + ppy, pc = pc0 + ppc;
        if (pr < 71 && pc < 71)
            out[((b * 32 + cog * 8 + co) * 71 + pr) * 71 + pc] = v;
    }
}

// ---------------------------------------------------------------------------
// Stage 2: conv2 (9x9, Cin=32, Cout=16) + ReLU. Output row stride 64 (padded)
// so lc1's patch rows have block-uniform alignment.
// ---------------------------------------------------------------------------
__global__ __launch_bounds__(256) void conv2_kernel(
    const float* __restrict__ in, const float* __restrict__ w,
    const float* __restrict__ bias, float* __restrict__ out)
{
    const int tile = blockIdx.x;
    const int b = blockIdx.y;
    const int ty = tile / 4, tx = tile % 4;
    const int oh0 = ty * 16, ow0 = tx * 16;

    __shared__ float in_s[4][24][25];
    __shared__ float w_s[16][324];

    const int tid = threadIdx.x;
    const int co = tid / 16;
    const int py = tid % 16;

    float acc[16];
    #pragma unroll
    for (int i = 0; i < 16; ++i) acc[i] = 0.f;

    for (int cc = 0; cc < 8; ++cc) {
        for (int i = tid; i < 4 * 24 * 24; i += 256) {
            int ci = i / 576, r = (i / 24) % 24, c = i % 24;
            int ih = oh0 + r, iw = ow0 + c;
            float v = 0.f;
            if (ih < 71 && iw < 71)
                v = in[((b * 32 + cc * 4 + ci) * 71 + ih) * 71 + iw];
            in_s[ci][r][c] = v;
        }
        for (int i = tid; i < 16 * 324; i += 256) {
            int c2 = i / 324, t = i % 324;
            w_s[c2][t] = w[c2 * 2592 + cc * 324 + t];
        }
        __syncthreads();

        #pragma unroll 1
        for (int ci = 0; ci < 4; ++ci) {
            #pragma unroll 1
            for (int kh = 0; kh < 9; ++kh) {
                float rr[24];
                #pragma unroll
                for (int c = 0; c < 24; ++c) rr[c] = in_s[ci][py + kh][c];
                #pragma unroll
                for (int kw = 0; kw < 9; ++kw) {
                    float wv = w_s[co][ci * 81 + kh * 9 + kw];
                    #pragma unroll
                    for (int px = 0; px < 16; ++px)
                        acc[px] += rr[kw + px] * wv;
                }
            }
        }
        __syncthreads();
    }

    const int oh = oh0 + py;
    if (oh < 63) {
        const float bv = bias[co];
        #pragma unroll
        for (int px = 0; px < 16; ++px) {
            int ow = ow0 + px;
            if (ow < 63)
                out[((b * 16 + co) * 63 + oh) * 64 + ow] = fmaxf(acc[px] + bv, 0.f);
        }
    }
}

// ---------------------------------------------------------------------------
// Stage 3 (lc1) v14: MFMA bf16x3, 1024-thread blocks + 2-deep kstep pipeline.
// vs v13 (241us): 16 waves/block -> 4 waves/SIMD (2x TLP); prefetch kstep
// s+16's A/B fragments while computing s (weight-load latency overlaps the
// split+3-MFMA chain instead of preceding it). Layouts verified in r16.
// Block = (pos, half); split-K over 16 waves (ksteps of 32, 41 total).
// ---------------------------------------------------------------------------
__global__ __launch_bounds__(1024) void lc1_mfma_kernel(
    const float* __restrict__ in, const float* __restrict__ w,
    const float* __restrict__ bias, float* __restrict__ out)
{
    constexpr int K     = 1296;
    constexpr int WPAD  = 64;
    constexpr int PLANE = 63 * WPAD;       // 4032
    constexpr int CHW   = 16 * PLANE;      // 64512
    constexpr int HW    = 55 * 55;
    constexpr int LSTR  = 1316;            // stride pad (mod 32 = 4)

    __shared__ float patch_f[16 * LSTR];   // 84,224 B
    __shared__ float red[16 * 256];        // 16,384 B

    const int tid = threadIdx.x;
    const int sb2 = xcd_swizzle(blockIdx.x, 2 * HW);
    const int pos = sb2 >> 1;
    const int half = sb2 & 1;
    const int oh = pos / 55, ow = pos % 55;
    const int sh = ow & 3;                 // block-uniform alignment shift
    const int gbase = oh * WPAD + (ow - sh);

    // ---- stage patch rows -> LDS (fp32, k-contiguous) ----
    const float* inb = in + half * 16 * CHW;
    for (int t = tid; t < 2304; t += 1024) {
        const int b    = t & 15;
        const int rest = t >> 4;           // ci*9 + kh  (0..143)
        const float* src = inb + b * CHW + (rest / 9) * PLANE
                         + gbase + (rest - (rest / 9) * 9) * WPAD;
        float4 f0 = *reinterpret_cast<const float4*>(src);
        float4 f1 = *reinterpret_cast<const float4*>(src + 4);
        float4 f2 = *reinterpret_cast<const float4*>(src + 8);
        float* p = &patch_f[b * LSTR + rest * 9];
        if (sh == 0) {
            p[0]=f0.x; p[1]=f0.y; p[2]=f0.z; p[3]=f0.w;
            p[4]=f1.x; p[5]=f1.y; p[6]=f1.z; p[7]=f1.w; p[8]=f2.x;
        } else if (sh == 1) {
            p[0]=f0.y; p[1]=f0.z; p[2]=f0.w; p[3]=f1.x;
            p[4]=f1.y; p[5]=f1.z; p[6]=f1.w; p[7]=f2.x; p[8]=f2.y;
        } else if (sh == 2) {
            p[0]=f0.z; p[1]=f0.w; p[2]=f1.x; p[3]=f1.y;
            p[4]=f1.z; p[5]=f1.w; p[6]=f2.x; p[7]=f2.y; p[8]=f2.z;
        } else {
            p[0]=f0.w; p[1]=f1.x; p[2]=f1.y; p[3]=f1.z;
            p[4]=f1.w; p[5]=f2.x; p[6]=f2.y; p[7]=f2.z; p[8]=f2.w;
        }
    }
    // zero k-tail 1296..1315
    for (int i = tid; i < 16 * 20; i += 1024)
        patch_f[(i / 20) * LSTR + 1296 + (i % 20)] = 0.f;
    __syncthreads();

    // ---- split-K MFMA compute, 2-deep pipelined ----
    const int wid  = tid >> 6;             // wave 0..15
    const int lane = tid & 63;
    const int bq = lane & 15;              // A row (b) / B col (co)
    const int kq = lane >> 4;              // 0..3 -> k-run (kq*8)

    f32x4 acc = {0.f, 0.f, 0.f, 0.f};
    const float* wpos = w + (size_t)pos * 16 * K + (size_t)bq * K;

    auto loadA = [&](int s, float* av) {
        const float* ap = &patch_f[bq * LSTR + s * 32 + kq * 8];
        *reinterpret_cast<float4*>(&av[0]) = *reinterpret_cast<const float4*>(ap);
        *reinterpret_cast<float4*>(&av[4]) = *reinterpret_cast<const float4*>(ap + 4);
    };
    auto loadB = [&](int s, float* wv) {
        const int k8 = s * 32 + kq * 8;
        if (k8 < K) {
            *reinterpret_cast<float4*>(&wv[0]) =
                *reinterpret_cast<const float4*>(wpos + k8);
            *reinterpret_cast<float4*>(&wv[4]) =
                *reinterpret_cast<const float4*>(wpos + k8 + 4);
        } else {
            #pragma unroll
            for (int j = 0; j < 8; ++j) wv[j] = 0.f;
        }
    };

    int s = wid;
    if (s < 41) {
        float av[8], wv[8], avn[8], wvn[8];
        loadB(s, wv);
        loadA(s, av);
        #pragma unroll 1
        while (true) {
            const int sn = s + 16;
            const bool more = (sn < 41);
            if (more) { loadB(sn, wvn); loadA(sn, avn); }
            bf16x8 ah, al, bh, bl;
            split_bf16(av, ah, al);
            split_bf16(wv, bh, bl);
            acc = __builtin_amdgcn_mfma_f32_16x16x32_bf16(ah, bh, acc, 0, 0, 0);
            acc = __builtin_amdgcn_mfma_f32_16x16x32_bf16(ah, bl, acc, 0, 0, 0);
            acc = __builtin_amdgcn_mfma_f32_16x16x32_bf16(al, bh, acc, 0, 0, 0);
            if (!more) break;
            #pragma unroll
            for (int j = 0; j < 8; ++j) { av[j] = avn[j]; wv[j] = wvn[j]; }
            s = sn;
        }
    }

    // ---- split-K reduce through LDS ----
    *reinterpret_cast<float4*>(&red[(wid * 64 + lane) * 4]) =
        make_float4(acc[0], acc[1], acc[2], acc[3]);
    __syncthreads();

    if (tid < 256) {
        const int L = tid & 63, r = tid >> 6;
        float s2 = 0.f;
        #pragma unroll
        for (int wv2 = 0; wv2 < 16; ++wv2)
            s2 += red[wv2 * 256 + L * 4 + r];
        const int row = (L >> 4) * 4 + r;      // m89-verified C/D mapping
        const int col = L & 15;
        const int b  = half * 16 + row;
        out[(b * 16 + col) * HW + pos] = fmaxf(s2 + bias[col * HW + pos], 0.f);
    }
}

// ---------------------------------------------------------------------------
// Stages 4-5 (lc2, lc3) v10: proven template, unchanged.
// ---------------------------------------------------------------------------
template<int KS, int STRIDE, int HIN, int WIN, int HOUT, int WOUT>
__global__ __launch_bounds__(512) void lc_v10_kernel(
    const float* __restrict__ in, const float* __restrict__ w,
    const float* __restrict__ bias, float* __restrict__ out)
{
    constexpr int K     = 16 * KS * KS;
    constexpr int K2    = KS * KS;
    constexpr int NPASS = (K + 127) / 128;
    constexpr int KPAD  = NPASS * 128;
    constexpr int HW    = HOUT * WOUT;
    constexpr int CHW   = 16 * HIN * WIN;

    __shared__ float patch_s[2][4096];
    __shared__ int   base_s[KPAD];

    const int tid = threadIdx.x;
    const int pos = xcd_swizzle(blockIdx.x, HW);
    const int oh = pos / WOUT, ow = pos % WOUT;
    const int posoff = (oh * STRIDE) * WIN + ow * STRIDE;

    for (int k = tid; k < KPAD; k += 512) {
        int v = 0;
        if (k < K) {
            int ci = k / K2;
            int r  = k - ci * K2;
            int kh = r / KS, kw = r - kh * KS;
            v = ci * (HIN * WIN) + kh * WIN + kw;
        }
        base_s[k] = v;
    }

    const int kl  = tid & 31;
    const int cog = (tid >> 5) & 3;
    const int bg  = tid >> 7;
    const int b0  = bg * 8;

    const int sb = tid >> 5;
    const int k0 = (tid & 31) * 4;
    const float* gsrc0 = in + sb * CHW + posoff;
    const float* gsrc1 = gsrc0 + 16 * CHW;

    const float* wbase = w + (size_t)pos * 16 * K;

    float acc[8][4];
    #pragma unroll
    for (int i = 0; i < 8; ++i)
        #pragma unroll
        for (int j = 0; j < 4; ++j) acc[i][j] = 0.f;

    __syncthreads();

    {
        int4 off4 = *reinterpret_cast<const int4*>(&base_s[k0]);
        float t0x = gsrc0[off4.x], t0y = gsrc0[off4.y],
              t0z = gsrc0[off4.z], t0w = gsrc0[off4.w];
        float t1x = gsrc1[off4.x], t1y = gsrc1[off4.y],
              t1z = gsrc1[off4.z], t1w = gsrc1[off4.w];
        *reinterpret_cast<float4*>(&patch_s[0][tid * 4]) =
            make_float4(t0x, t0y, t0z, t0w);
        *reinterpret_cast<float4*>(&patch_s[0][2048 + tid * 4]) =
            make_float4(t1x, t1y, t1z, t1w);
    }
    asm volatile("s_waitcnt lgkmcnt(0)" ::: "memory");
    __builtin_amdgcn_s_barrier();

    int cur = 0;
    #pragma unroll 1
    for (int ps = 0; ps < NPASS; ++ps) {
        const bool more = (ps + 1 < NPASS);
        float4 wv[4];
        {
            const int kw4 = ps * 128 + kl * 4;
            #pragma unroll
            for (int cj = 0; cj < 4; ++cj)
                wv[cj] = (kw4 < K)
                    ? *reinterpret_cast<const float4*>(wbase + (size_t)(cog * 4 + cj) * K + kw4)
                    : make_float4(0.f, 0.f, 0.f, 0.f);
        }
        float t0x, t0y, t0z, t0w, t1x, t1y, t1z, t1w;
        if (more) {
            int4 off4 = *reinterpret_cast<const int4*>(&base_s[(ps + 1) * 128 + k0]);
            t0x = gsrc0[off4.x]; t0y = gsrc0[off4.y];
            t0z = gsrc0[off4.z]; t0w = gsrc0[off4.w];
            t1x = gsrc1[off4.x]; t1y = gsrc1[off4.y];
            t1z = gsrc1[off4.z]; t1w = gsrc1[off4.w];
        }
        #pragma unroll
        for (int bi = 0; bi < 8; ++bi) {
            float4 pv = *reinterpret_cast<const float4*>(
                &patch_s[cur][(b0 + bi) * 128 + kl * 4]);
            #pragma unroll
            for (int cj = 0; cj < 4; ++cj)
                acc[bi][cj] += pv.x * wv[cj].x + pv.y * wv[cj].y
                             + pv.z * wv[cj].z + pv.w * wv[cj].w;
        }
        if (more) {
            *reinterpret_cast<float4*>(&patch_s[cur ^ 1][tid * 4]) =
                make_float4(t0x, t0y, t0z, t0w);
            *reinterpret_cast<float4*>(&patch_s[cur ^ 1][2048 + tid * 4]) =
                make_float4(t1x, t1y, t1z, t1w);
        }
        asm volatile("s_waitcnt lgkmcnt(0)" ::: "memory");
        __builtin_amdgcn_s_barrier();
        cur ^= 1;
    }

    #pragma unroll
    for (int bi = 0; bi < 8; ++bi)
        #pragma unroll
        for (int cj = 0; cj < 4; ++cj) {
            float v = acc[bi][cj];
            v += __shfl_xor(v, 1);
            v += __shfl_xor(v, 2);
            v += __shfl_xor(v, 4);
            v += __shfl_xor(v, 8);
            v += __shfl_xor(v, 16);
            acc[bi][cj] = v;
        }

    if (kl == 0) {
        float bv[4];
        #pragma unroll
        for (int cj = 0; cj < 4; ++cj)
            bv[cj] = bias[(cog * 4 + cj) * HW + pos];
        #pragma unroll
        for (int bi = 0; bi < 8; ++bi)
            #pragma unroll
            for (int cj = 0; cj < 4; ++cj) {
                int b = b0 + bi, co = cog * 4 + cj;
                out[(b * 16 + co) * HW + pos] = fmaxf(acc[bi][cj] + bv[cj], 0.f);
            }
    }
}

// ---------------------------------------------------------------------------
// Stage 6 v5: FC (32,7056)@(4096,7056)^T, LDS-pipelined (round-8 proven).
// ---------------------------------------------------------------------------
__global__ __launch_bounds__(512) void fc_v5_kernel(
    const float* __restrict__ in, const float* __restrict__ w,
    float* __restrict__ part)
{
    constexpr int K = 7056, KR = 1764;
    constexpr int NPASS = (KR + 127) / 128;   // 14

    __shared__ float patch_s[2][4096];

    const int tid  = threadIdx.x;
    const int oblk = blockIdx.x;
    const int ks   = blockIdx.y;
    const int kbeg = ks * KR, klim = kbeg + KR;

    const int kl  = tid & 31;
    const int cog = (tid >> 5) & 3;
    const int bg  = tid >> 7;
    const int b0  = bg * 8;

    const int sb = tid >> 5;
    const int k0 = (tid & 31) * 4;
    const float* row0 = in + sb * K;
    const float* row1 = row0 + 16 * K;

    const float* wbase = w + (size_t)(oblk * 16) * K;

    auto ld4 = [&](const float* row, int kg) -> float4 {
        return (kg < klim) ? *reinterpret_cast<const float4*>(row + kg)
                           : make_float4(0.f, 0.f, 0.f, 0.f);
    };

    float acc[8][4];
    #pragma unroll
    for (int i = 0; i < 8; ++i)
        #pragma unroll
        for (int j = 0; j < 4; ++j) acc[i][j] = 0.f;

    float4 wv[4], wvn[4];
    float4 t0, t1;

    {
        const int kw4 = kbeg + kl * 4;
        #pragma unroll
        for (int cj = 0; cj < 4; ++cj)
            wv[cj] = (kw4 < klim)
                ? *reinterpret_cast<const float4*>(wbase + (size_t)(cog * 4 + cj) * K + kw4)
                : make_float4(0.f, 0.f, 0.f, 0.f);
        t0 = ld4(row0, kbeg + k0);
        t1 = ld4(row1, kbeg + k0);
        *reinterpret_cast<float4*>(&patch_s[0][tid * 4]) = t0;
        *reinterpret_cast<float4*>(&patch_s[0][2048 + tid * 4]) = t1;
    }
    __syncthreads();

    int cur = 0;
    #pragma unroll 1
    for (int ps = 0; ps < NPASS; ++ps) {
        const bool more = (ps + 1 < NPASS);
        if (more) {
            const int kbn = kbeg + (ps + 1) * 128;
            t0 = ld4(row0, kbn + k0);
            t1 = ld4(row1, kbn + k0);
            const int kw4n = kbn + kl * 4;
            #pragma unroll
            for (int cj = 0; cj < 4; ++cj)
                wvn[cj] = (kw4n < klim)
                    ? *reinterpret_cast<const float4*>(wbase + (size_t)(cog * 4 + cj) * K + kw4n)
                    : make_float4(0.f, 0.f, 0.f, 0.f);
        }
        #pragma unroll
        for (int bi = 0; bi < 8; ++bi) {
            float4 pv = *reinterpret_cast<const float4*>(
                &patch_s[cur][(b0 + bi) * 128 + kl * 4]);
            #pragma unroll
            for (int cj = 0; cj < 4; ++cj)
                acc[bi][cj] += pv.x * wv[cj].x + pv.y * wv[cj].y
                             + pv.z * wv[cj].z + pv.w * wv[cj].w;
        }
        if (more) {
            *reinterpret_cast<float4*>(&patch_s[cur ^ 1][tid * 4]) = t0;
            *reinterpret_cast<float4*>(&patch_s[cur ^ 1][2048 + tid * 4]) = t1;
            #pragma unroll
            for (int cj = 0; cj < 4; ++cj) wv[cj] = wvn[cj];
        }
        __syncthreads();
        cur ^= 1;
    }

    #pragma unroll
    for (int bi = 0; bi < 8; ++bi)
        #pragma unroll
        for (int cj = 0; cj < 4; ++cj) {
            float v = acc[bi][cj];
            v += __shfl_xor(v, 1);
            v += __shfl_xor(v, 2);
            v += __shfl_xor(v, 4);
            v += __shfl_xor(v, 8);
            v += __shfl_xor(v, 16);
            acc[bi][cj] = v;
        }

    if (kl == 0) {
        #pragma unroll
        for (int bi = 0; bi < 8; ++bi)
            #pragma unroll
            for (int cj = 0; cj < 4; ++cj)
                part[(size_t)(ks * 32 + b0 + bi) * 4096 + oblk * 16 + cog * 4 + cj] =
                    acc[bi][cj];
    }
}

__global__ __launch_bounds__(256) void fc_reduce_kernel(
    const float* __restrict__ part, const float* __restrict__ bias,
    float* __restrict__ out)
{
    int i4 = blockIdx.x * 256 + threadIdx.x;
    if (i4 >= 32768) return;
    int b = i4 >> 10, o4 = i4 & 1023;
    const size_t stride = (size_t)32 * 4096;
    const float* base = part + (size_t)b * 4096 + o4 * 4;
    float4 s0 = *reinterpret_cast<const float4*>(base);
    float4 s1 = *reinterpret_cast<const float4*>(base + stride);
    float4 s2 = *reinterpret_cast<const float4*>(base + 2 * stride);
    float4 s3 = *reinterpret_cast<const float4*>(base + 3 * stride);
    float4 bv = *reinterpret_cast<const float4*>(bias + o4 * 4);
    float4 r;
    r.x = s0.x + s1.x + s2.x + s3.x + bv.x;
    r.y = s0.y + s1.y + s2.y + s3.y + bv.y;
    r.z = s0.z + s1.z + s2.z + s3.z + bv.z;
    r.w = s0.w + s1.w + s2.w + s3.w + bv.w;
    *reinterpret_cast<float4*>(out + b * 4096 + o4 * 4) = r;
}

// ---------------------------------------------------------------------------
extern "C" void kernel_launch(void* const* d_in, const int* in_sizes, int n_in,
                              void* d_out, int out_size, void* d_ws, size_t ws_size,
                              hipStream_t stream) {
    const float* x    = (const float*)d_in[0];
    const float* c1w  = (const float*)d_in[1];
    const float* c1b  = (const float*)d_in[2];
    const float* c2w  = (const float*)d_in[3];
    const float* c2b  = (const float*)d_in[4];
    const float* lc1w = (const float*)d_in[5];
    const float* lc1b = (const float*)d_in[6];
    const float* lc2w = (const float*)d_in[7];
    const float* lc2b = (const float*)d_in[8];
    const float* lc3w = (const float*)d_in[9];
    const float* lc3b = (const float*)d_in[10];
    const float* fcw  = (const float*)d_in[11];
    const float* fcb  = (const float*)d_in[12];
    float* out = (float*)d_out;

    float* ws  = (float*)d_ws;
    float* h1p = ws;                 // 32*32*71*71 = 5,161,472
    float* h2  = h1p + 5161472;      // padded: 32*16*63*64 = 2,064,384 (+64 pad)
    float* h3  = h2  + 2064448;      // 32*16*55*55 = 1,548,800
    float* h4  = h3  + 1548800;      // 32*16*25*25 =   320,000
    float* h5  = h4  + 320000;       // 32*16*21*21 =   225,792
    float* fc_part = h1p;            // conv1 output dead by fc time

    conv1_pool_v2_kernel<<<dim3(25, 4, 32), 256, 0, stream>>>(x, c1w, c1b, h1p);
    conv2_kernel<<<dim3(16, 32), 256, 0, stream>>>(h1p, c2w, c2b, h2);
    lc1_mfma_kernel<<<dim3(55 * 55 * 2), 1024, 0, stream>>>(h2, lc1w, lc1b, h3);
    lc_v10_kernel<7, 2, 55, 55, 25, 25><<<dim3(25 * 25), 512, 0, stream>>>(h3, lc2w, lc2b, h4);
    lc_v10_kernel<5, 1, 25, 25, 21, 21><<<dim3(21 * 21), 512, 0, stream>>>(h4, lc3w, lc3b, h5);
    fc_v5_kernel<<<dim3(256, 4), 512, 0, stream>>>(h5, fcw, fc_part);
    fc_reduce_kernel<<<dim3(128), 256, 0, stream>>>(fc_part, fcb, out);
}